// Round 18
// baseline (867.144 us; speedup 1.0000x reference)
//
#include <hip/hip_runtime.h>
#include <hip/hip_bf16.h>
#include <math.h>

typedef unsigned short u16;
typedef __attribute__((ext_vector_type(4))) unsigned short us4;
typedef __attribute__((ext_vector_type(8))) unsigned short us8;
typedef __attribute__((ext_vector_type(8))) short s8v;   // mfma bf16 operand (4 VGPRs)
typedef __attribute__((ext_vector_type(4))) float f4v;   // mfma accum

#define BB 2
#define TT 1024
#define CC 2048
#define HH 32
#define BT (BB*TT)

// Inputs/outputs fp32. ws intermediates bf16: 7 regions x NBTC u16.
// All GEMMs (including the skinny w1 projections) run on MFMA via mgemm_k;
// EPI_H writes activated bf16 hidden states with zero-padded pitch so the
// downstream padded-K MFMA sees exact zeros. prep12_k fuses per-step prep +
// pair compounding (R17). rec_k = R13 pair form (g=16, 2 steps/iter).

__device__ __forceinline__ float bf2f(u16 u) {
  return __uint_as_float(((unsigned int)u) << 16);
}
__device__ __forceinline__ u16 f2bf(float f) {
  unsigned int x = __float_as_uint(f);
  x += 0x7fffu + ((x >> 16) & 1u);
  return (u16)(x >> 16);
}

// async global->LDS, 16B per lane; lptr must be the wave-uniform base
// (HW writes base + lane*16 -- m104 semantics).
__device__ __forceinline__ void gload16(const u16* g, u16* l) {
  __builtin_amdgcn_global_load_lds(
      (const __attribute__((address_space(1))) void*)g,
      (__attribute__((address_space(3))) void*)l, 16, 0, 0);
}

// ---------------------------------------------------------------- mix kernel
__global__ __launch_bounds__(256)
void mix_k(const float* __restrict__ x, const float* __restrict__ s,
           u16* __restrict__ out) {
  int idx = blockIdx.x * 256 + threadIdx.x;       // over BT*C
  int c = idx & (CC - 1);
  int t = (idx >> 11) & (TT - 1);
  float xv = x[idx];
  float xp = (t == 0) ? 0.f : x[idx - CC];
  out[idx] = f2bf(xv + (xp - xv) * s[c]);
}

// ---------------------------------------------------------------- weight cvt-transpose
// W fp32 [K][N] -> Wt bf16 [N][Kp] (pitch Kp). 32x32 tiles, 256 threads.
__global__ __launch_bounds__(256)
void wt_k(const float* __restrict__ W, u16* __restrict__ Wt, int K, int N,
          int Kp) {
  __shared__ u16 tile[32][36];
  const int k0 = blockIdx.x * 32, n0 = blockIdx.y * 32;
  const int tid = threadIdx.x;
  const int r = tid >> 3, c4 = (tid & 7) << 2;
  float4 v = *(const float4*)(W + (size_t)(k0 + r) * N + n0 + c4);
  tile[r][c4 + 0] = f2bf(v.x); tile[r][c4 + 1] = f2bf(v.y);
  tile[r][c4 + 2] = f2bf(v.z); tile[r][c4 + 3] = f2bf(v.w);
  __syncthreads();
  ushort4 o;
  o.x = tile[c4 + 0][r]; o.y = tile[c4 + 1][r];
  o.z = tile[c4 + 2][r]; o.w = tile[c4 + 3][r];
  *(ushort4*)(Wt + (size_t)(n0 + r) * Kp + k0 + c4) = o;
}

// ---------------------------------------------------------------- MFMA GEMM
// C[M,N] = A[M,lda](bf16) * Bt[N,ldb](bf16, row n = col n of B), fp32 accum.
// Block tile 128x128, BK=64, 4 waves (2x2), wave tile 64x64 = 4x4 frags.
// Staging: global_load_lds width 16, linear LDS [128][64] u16; both-sides
// XOR swizzle by (row&7) on 16B units (rule #21) -> conflict-free ds_read.
// N param is the OUTPUT PITCH (ldc). EPI_H: bf16 hidden with runtime act
// (0 none / 1 tanh / 2 sigmoid), cols < Dlim = act(acc), Dlim<=col<Dpad = 0.
enum { EPI_BF = 0, EPI_F32 = 1, EPI_BIAS_SP = 2, EPI_BIAS_SIG = 3,
       EPI_VMIX = 4, EPI_H = 5 };

template<int EPI>
__global__ __launch_bounds__(256)
void mgemm_k(const u16* __restrict__ A, const u16* __restrict__ Bt,
             float* __restrict__ outF, u16* __restrict__ outB,
             int M, int N, int K, int lda, int ldb,
             int Dlim, int Dpad, int act,
             const float* __restrict__ bias, const u16* __restrict__ p1,
             const float* __restrict__ p2)
{
  __shared__ alignas(16) u16 As[128 * 64];
  __shared__ alignas(16) u16 Bs[128 * 64];
  const int m0 = blockIdx.x * 128;
  const int n0 = blockIdx.y * 128;
  const int tid = threadIdx.x;
  const int lane = tid & 63;
  const int wid = tid >> 6;
  const int wr = wid >> 1, wc = wid & 1;        // wave quadrant (2x2)
  f4v acc[4][4];
  #pragma unroll
  for (int i = 0; i < 4; ++i)
    #pragma unroll
    for (int j = 0; j < 4; ++j) acc[i][j] = f4v{0.f, 0.f, 0.f, 0.f};

  const int l15 = lane & 15;
  const int lq = lane >> 4;                     // 0..3
  const int nkt = K >> 6;
  for (int kt = 0; kt < nkt; ++kt) {
    const int k0 = kt << 6;
    __syncthreads();                            // prev compute done
    #pragma unroll
    for (int a = 0; a < 4; ++a) {
      const int blkU = (wid * 4 + a) * 64;      // wave-uniform unit base
      const int U = blkU + lane;                // this lane's unit
      const int row = U >> 3;
      const int u = U & 7;
      const int col = ((u ^ (row & 7)) << 3);   // pre-swizzled source col
      gload16(A  + (size_t)(m0 + row) * lda + k0 + col, &As[blkU * 8]);
      gload16(Bt + (size_t)(n0 + row) * ldb + k0 + col, &Bs[blkU * 8]);
    }
    __syncthreads();                            // vmcnt drained -> LDS ready
    #pragma unroll
    for (int h = 0; h < 2; ++h) {
      s8v af[4], bfr[4];
      #pragma unroll
      for (int i = 0; i < 4; ++i) {
        const int row = wr * 64 + i * 16 + l15;
        const int u = (h * 4 + lq) ^ (row & 7); // swizzled read unit
        af[i] = *(const s8v*)&As[row * 64 + u * 8];
      }
      #pragma unroll
      for (int j = 0; j < 4; ++j) {
        const int row = wc * 64 + j * 16 + l15;
        const int u = (h * 4 + lq) ^ (row & 7);
        bfr[j] = *(const s8v*)&Bs[row * 64 + u * 8];
      }
      #pragma unroll
      for (int i = 0; i < 4; ++i)
        #pragma unroll
        for (int j = 0; j < 4; ++j)
          acc[i][j] = __builtin_amdgcn_mfma_f32_16x16x32_bf16(af[i], bfr[j],
                                                              acc[i][j],
                                                              0, 0, 0);
    }
  }
  // C/D layout: col = lane&15, row = (lane>>4)*4 + q  (m89-verified)
  const int rbase = m0 + wr * 64 + (lq << 2);
  const int cbase = n0 + wc * 64 + l15;
  #pragma unroll
  for (int i = 0; i < 4; ++i) {
    #pragma unroll
    for (int j = 0; j < 4; ++j) {
      f4v c = acc[i][j];
      const int col = cbase + j * 16;
      #pragma unroll
      for (int q = 0; q < 4; ++q) {
        const int row = rbase + i * 16 + q;
        const float r = c[q];
        if (EPI == EPI_H) {
          if (col < Dlim) {
            float t = r;
            if (act == 1) t = tanhf(t);
            else if (act == 2) t = 1.f / (1.f + expf(-t));
            outB[(size_t)row * N + col] = f2bf(t);
          } else if (col < Dpad) {
            outB[(size_t)row * N + col] = 0;
          }
          continue;
        }
        const size_t idx = (size_t)row * N + col;
        if (EPI == EPI_BF) {
          outB[idx] = f2bf(r);
        } else if (EPI == EPI_F32) {
          outF[idx] = r;
        } else if (EPI == EPI_BIAS_SP) {
          float u = bias[col] + r;
          float z = -u;
          float sp = fmaxf(z, 0.f) + log1pf(expf(-fabsf(z)));
          outB[idx] = f2bf(-sp - 0.5f);
        } else if (EPI == EPI_BIAS_SIG) {
          float u = bias[col] + r;
          outB[idx] = f2bf(1.f / (1.f + expf(-u)));
        } else if (EPI == EPI_VMIX) {
          float u = bias[col] + r;
          float sg = 1.f / (1.f + expf(-u));
          float v = bf2f(p1[idx]);
          float v0v = p2[idx];
          outB[idx] = f2bf(v + (v0v - v) * sg);
        }
      }
    }
  }
}

// ---------------------------------------------------------------- fused pair prep
// Wave per (b,tp,h), lane = j. Computes BOTH steps (t=2tp, 2tp+1) of the
// per-step prep in registers, then writes the R12-compounded vectors
// directly. In-place aliases are safe: every location is read once then
// written once by the same lane; all loads precede all stores.
__global__ __launch_bounds__(256)
void prep12_k(const u16* __restrict__ k_in, const u16* __restrict__ a_in,
              const u16* __restrict__ r_in, const u16* __restrict__ w_in,
              const float* __restrict__ kk_s, const float* __restrict__ ka_s,
              u16* __restrict__ ao_out, u16* __restrict__ bo_out,
              u16* __restrict__ k_out, u16* __restrict__ wd_out,
              u16* __restrict__ rw_out, float2* __restrict__ scal,
              float4* __restrict__ scal4)
{
  const int tid = threadIdx.x;
  const int lane = tid & 63;
  const int hpidx = blockIdx.x * 4 + (tid >> 6);  // (b*T/2+tp)*H + h
  const int h = hpidx & (HH - 1);
  const int btp = hpidx >> 5;
  const int tp = btp & (TT / 2 - 1);
  const int b = btp >> 9;                          // TT/2 = 512
  const int c = (h << 6) + lane;
  const size_t be = ((size_t)(b * TT + 2 * tp)) * CC + (h << 6) + lane;
  const size_t bod = be + CC;
  const float ks = kk_s[c], kas = ka_s[c];
  const float k1 = bf2f(k_in[be]),  k2 = bf2f(k_in[bod]);
  const float a1 = bf2f(a_in[be]),  a2 = bf2f(a_in[bod]);
  const float r1 = bf2f(r_in[be]),  r2 = bf2f(r_in[bod]);
  const float wraw1 = bf2f(w_in[be]), wraw2 = bf2f(w_in[bod]);
  float kk1 = k1 * ks, kk2 = k2 * ks;
  float ss1 = kk1 * kk1, ss2 = kk2 * kk2;
  #pragma unroll
  for (int off = 32; off; off >>= 1) {
    ss1 += __shfl_xor(ss1, off, 64);
    ss2 += __shfl_xor(ss2, off, 64);
  }
  const float kkn1 = kk1 / fmaxf(sqrtf(ss1), 1e-12f);
  const float kkn2 = kk2 / fmaxf(sqrtf(ss2), 1e-12f);
  const float kf1 = k1 * (1.f + (a1 - 1.f) * kas);
  const float kf2 = k2 * (1.f + (a2 - 1.f) * kas);
  const float wd1 = expf(-expf(wraw1));
  const float wd2 = expf(-expf(wraw2));
  const float ao1 = -kkn1, ao2 = -kkn2;
  const float bo1 = kkn1 * a1, bo2 = kkn2 * a2;
  const float rw1 = wd1 * r1, rw2 = wd2 * r2;
  float kr1 = kf1 * r1, br1 = bo1 * r1;
  float kr2 = kf2 * r2, br2 = bo2 * r2;
  float cba = bo1 * ao2, ckb = kf1 * ao2;
  float crb = bo1 * rw2, crk = kf1 * rw2;
  #pragma unroll
  for (int off = 32; off; off >>= 1) {
    kr1 += __shfl_xor(kr1, off, 64);  br1 += __shfl_xor(br1, off, 64);
    kr2 += __shfl_xor(kr2, off, 64);  br2 += __shfl_xor(br2, off, 64);
    cba += __shfl_xor(cba, off, 64);  ckb += __shfl_xor(ckb, off, 64);
    crb += __shfl_xor(crb, off, 64);  crk += __shfl_xor(crk, off, 64);
  }
  ao_out[be]  = f2bf(ao1);
  ao_out[bod] = f2bf(wd1 * ao2);
  bo_out[be]  = f2bf(bo1 * wd2);
  bo_out[bod] = f2bf(bo2);
  k_out[be]   = f2bf(kf1);
  k_out[bod]  = f2bf(kf2);
  wd_out[be]  = f2bf(wd1 * wd2);
  wd_out[bod] = f2bf(kf1 * wd2);
  rw_out[be]  = f2bf(rw1);
  rw_out[bod] = f2bf(wd1 * rw2);
  if (lane == 0) {
    const int se = (b * TT + 2 * tp) * HH + h;
    scal[se]      = make_float2(kr1, br1);
    scal[se + HH] = make_float2(kr2, br2);
    scal4[hpidx]  = make_float4(cba, ckb, crb, crk);
  }
}

// ---------------------------------------------------------------- RWKV7 recurrence
// g=16 geometry + 2-step compounding (R13 form): one iteration advances TWO
// timesteps with a single 4-level butterfly round of 4 interleaved
// reductions (u1,u2,q1,q2) on the same pre-pair state.
__global__ __launch_bounds__(256)
void rec_k(const u16* __restrict__ rw, const u16* __restrict__ wd,
           const u16* __restrict__ kv, const u16* __restrict__ v,
           const u16* __restrict__ ao, const u16* __restrict__ bo,
           const float2* __restrict__ scal, const float4* __restrict__ scal4,
           u16* __restrict__ y)
{
  const int gw = blockIdx.x * 4 + (threadIdx.x >> 6);   // 0..1023
  const int lane = threadIdx.x & 63;
  const int sub = lane & 15;
  const int grp = lane >> 4;
  const int bh = gw >> 4;
  const int rblk = gw & 15;
  const int i = rblk * 4 + grp;
  const int b = bh >> 5, h = bh & (HH - 1);
  const size_t base0 = ((size_t)b * TT) * CC + (h << 6);
  const size_t vecb = base0 + (sub << 2);
  const size_t vb   = base0 + i;
  const int sbase = b * TT * HH + h;
  const int pbase = b * (TT / 2) * HH + h;
  float s0 = 0.f, s1 = 0.f, s2 = 0.f, s3 = 0.f;

  us4 W12, KW1, AO1, WA2, BW1, BO2, RW1, WR2, K2;
  float V1, V2; float2 SE, SO; float4 S4;
#define PLOAD(TP) do {                                                  \
    const size_t be_ = vecb + (size_t)(2 * (TP)) * CC;                  \
    const size_t bo_ = be_ + CC;                                        \
    W12 = *(const us4*)(wd + be_);  KW1 = *(const us4*)(wd + bo_);      \
    AO1 = *(const us4*)(ao + be_);  WA2 = *(const us4*)(ao + bo_);      \
    BW1 = *(const us4*)(bo + be_);  BO2 = *(const us4*)(bo + bo_);      \
    RW1 = *(const us4*)(rw + be_);  WR2 = *(const us4*)(rw + bo_);      \
    K2  = *(const us4*)(kv + bo_);                                      \
    V1 = bf2f(v[vb + (size_t)(2 * (TP)) * CC]);                         \
    V2 = bf2f(v[vb + (size_t)(2 * (TP) + 1) * CC]);                     \
    SE = scal[sbase + (2 * (TP)) * HH];                                 \
    SO = scal[sbase + (2 * (TP) + 1) * HH];                             \
    S4 = scal4[pbase + (TP) * HH];                                      \
  } while (0)

  PLOAD(0);
  for (int tp = 0; tp < TT / 2; ++tp) {
    const float w0 = bf2f(W12[0]), w1 = bf2f(W12[1]),
                w2 = bf2f(W12[2]), w3 = bf2f(W12[3]);
    const float kw0 = bf2f(KW1[0]), kw1_ = bf2f(KW1[1]),
                kw2 = bf2f(KW1[2]), kw3 = bf2f(KW1[3]);
    const float a0 = bf2f(AO1[0]), a1 = bf2f(AO1[1]),
                a2 = bf2f(AO1[2]), a3 = bf2f(AO1[3]);
    const float x0 = bf2f(WA2[0]), x1 = bf2f(WA2[1]),
                x2 = bf2f(WA2[2]), x3 = bf2f(WA2[3]);
    const float bw0 = bf2f(BW1[0]), bw1_ = bf2f(BW1[1]),
                bw2 = bf2f(BW1[2]), bw3 = bf2f(BW1[3]);
    const float b0 = bf2f(BO2[0]), b1 = bf2f(BO2[1]),
                b2 = bf2f(BO2[2]), b3 = bf2f(BO2[3]);
    const float e0 = bf2f(RW1[0]), e1 = bf2f(RW1[1]),
                e2 = bf2f(RW1[2]), e3 = bf2f(RW1[3]);
    const float f0 = bf2f(WR2[0]), f1 = bf2f(WR2[1]),
                f2 = bf2f(WR2[2]), f3 = bf2f(WR2[3]);
    const float k0 = bf2f(K2[0]), k1 = bf2f(K2[1]),
                k2 = bf2f(K2[2]), k3 = bf2f(K2[3]);
    const float v1c = V1, v2c = V2;
    const float kr1 = SE.x, br1 = SE.y, kr2 = SO.x, br2 = SO.y;
    const float cba = S4.x, ckb = S4.y, crb = S4.z, crk = S4.w;
    if (tp + 1 < TT / 2) PLOAD(tp + 1);
    float u1 = fmaf(s3, a3, fmaf(s2, a2, fmaf(s1, a1, s0 * a0)));
    float u2 = fmaf(s3, x3, fmaf(s2, x2, fmaf(s1, x1, s0 * x0)));
    float q1 = fmaf(s3, e3, fmaf(s2, e2, fmaf(s1, e1, s0 * e0)));
    float q2 = fmaf(s3, f3, fmaf(s2, f2, fmaf(s1, f1, s0 * f0)));
    u1 += __shfl_xor(u1, 1, 64);  u2 += __shfl_xor(u2, 1, 64);
    q1 += __shfl_xor(q1, 1, 64);  q2 += __shfl_xor(q2, 1, 64);
    u1 += __shfl_xor(u1, 2, 64);  u2 += __shfl_xor(u2, 2, 64);
    q1 += __shfl_xor(q1, 2, 64);  q2 += __shfl_xor(q2, 2, 64);
    u1 += __shfl_xor(u1, 4, 64);  u2 += __shfl_xor(u2, 4, 64);
    q1 += __shfl_xor(q1, 4, 64);  q2 += __shfl_xor(q2, 4, 64);
    u1 += __shfl_xor(u1, 8, 64);  u2 += __shfl_xor(u2, 8, 64);
    q1 += __shfl_xor(q1, 8, 64);  q2 += __shfl_xor(q2, 8, 64);
    const float sac = fmaf(ckb, v1c, fmaf(cba, u1, u2));
    const float y1 = fmaf(br1, u1, fmaf(kr1, v1c, q1));
    const float y2 = fmaf(br2, sac, fmaf(kr2, v2c,
                       fmaf(crb, u1, fmaf(crk, v1c, q2))));
    s0 = fmaf(v2c, k0, fmaf(v1c, kw0, fmaf(sac, b0, fmaf(u1, bw0, s0 * w0))));
    s1 = fmaf(v2c, k1, fmaf(v1c, kw1_, fmaf(sac, b1, fmaf(u1, bw1_, s1 * w1))));
    s2 = fmaf(v2c, k2, fmaf(v1c, kw2, fmaf(sac, b2, fmaf(u1, bw2, s2 * w2))));
    s3 = fmaf(v2c, k3, fmaf(v1c, kw3, fmaf(sac, b3, fmaf(u1, bw3, s3 * w3))));
    if (sub == 0) {
      y[vb + (size_t)(2 * tp) * CC] = f2bf(y1);
      y[vb + (size_t)(2 * tp + 1) * CC] = f2bf(y2);
    }
  }
#undef PLOAD
}

// ---------------------------------------------------------------- GroupNorm + bonus + gate
__global__ __launch_bounds__(256)
void gn_k(u16* __restrict__ y, const u16* __restrict__ r,
          const u16* __restrict__ k, const u16* __restrict__ v,
          const u16* __restrict__ g, const float* __restrict__ rk_s,
          const float* __restrict__ gn_w, const float* __restrict__ gn_b)
{
  int tid = threadIdx.x, lane = tid & 63, wv = tid >> 6;
  int hidx = blockIdx.x * 4 + wv;
  int h = hidx & (HH - 1);
  int c = (h << 6) + lane;
  size_t base = ((size_t)hidx << 6) + lane;
  float yv = bf2f(y[base]), rv = bf2f(r[base]), kv = bf2f(k[base]);
  float vv = bf2f(v[base]), gv = bf2f(g[base]);
  float bsum = rv * kv * rk_s[c];
  float s1 = yv, s2 = yv * yv;
  for (int off = 32; off; off >>= 1) {
    s1 += __shfl_xor(s1, off, 64);
    s2 += __shfl_xor(s2, off, 64);
    bsum += __shfl_xor(bsum, off, 64);
  }
  float mu = s1 * (1.f / 64.f);
  float var = s2 * (1.f / 64.f) - mu * mu;
  float rstd = rsqrtf(var + 0.00064f);
  float z = (yv - mu) * rstd * gn_w[c] + gn_b[c];
  y[base] = f2bf((z + bsum * vv) * gv);
}

// ---------------------------------------------------------------- helpers
__global__ __launch_bounds__(256)
void copy_v0(const float* __restrict__ v0, float* __restrict__ out) {
  int idx = blockIdx.x * 256 + threadIdx.x;
  ((float4*)out)[idx] = ((const float4*)v0)[idx];
}

__global__ __launch_bounds__(256)
void zero_out(float* __restrict__ out) {
  int idx = blockIdx.x * 256 + threadIdx.x;
  ((float4*)out)[idx] = make_float4(0.f, 0.f, 0.f, 0.f);
}

// ----------------------------------------------------------------
extern "C" void kernel_launch(void* const* d_in, const int* in_sizes, int n_in,
                              void* d_out, int out_size, void* d_ws, size_t ws_size,
                              hipStream_t stream) {
  (void)n_in; (void)out_size;
  const bool dictOrder = (in_sizes[9] == CC);
  int IX[28];
  if (dictOrder) {
    const int m[28] = {0,1,2,3,4,5,6,7, 8,13,14, 9,15,16, 10,17,18, 19,20,
                       11,12,21, 22,23,24,25, 26,27};
    for (int i = 0; i < 28; ++i) IX[i] = m[i];
  } else {
    for (int i = 0; i < 28; ++i) IX[i] = i;
  }
  const float* x     = (const float*)d_in[IX[0]];
  const float* v0    = (const float*)d_in[IX[1]];
  const float* xx_r  = (const float*)d_in[IX[2]];
  const float* xx_w  = (const float*)d_in[IX[3]];
  const float* xx_k  = (const float*)d_in[IX[4]];
  const float* xx_v  = (const float*)d_in[IX[5]];
  const float* xx_a  = (const float*)d_in[IX[6]];
  const float* xx_g  = (const float*)d_in[IX[7]];
  const float* ww_b  = (const float*)d_in[IX[8]];
  const float* ww_w1 = (const float*)d_in[IX[9]];
  const float* ww_w2 = (const float*)d_in[IX[10]];
  const float* aa_b  = (const float*)d_in[IX[11]];
  const float* aa_w1 = (const float*)d_in[IX[12]];
  const float* aa_w2 = (const float*)d_in[IX[13]];
  const float* vv_b  = (const float*)d_in[IX[14]];
  const float* vv_w1 = (const float*)d_in[IX[15]];
  const float* vv_w2 = (const float*)d_in[IX[16]];
  const float* gg_w1 = (const float*)d_in[IX[17]];
  const float* gg_w2 = (const float*)d_in[IX[18]];
  const float* kk_s  = (const float*)d_in[IX[19]];
  const float* ka_s  = (const float*)d_in[IX[20]];
  const float* rk_s  = (const float*)d_in[IX[21]];
  const float* W_r   = (const float*)d_in[IX[22]];
  const float* W_k   = (const float*)d_in[IX[23]];
  const float* W_v   = (const float*)d_in[IX[24]];
  const float* W_o   = (const float*)d_in[IX[25]];
  const float* gn_w  = (const float*)d_in[IX[26]];
  const float* gn_b  = (const float*)d_in[IX[27]];

  const size_t NBTC = (size_t)BT * CC;
  dim3 blk(256);
  const int grid4f = (int)(NBTC / 4 / 256);

  const size_t WS_NEED = 7 * NBTC * sizeof(u16);
  float* outF = (float*)d_out;
  if (ws_size < WS_NEED || d_ws == nullptr) {
    zero_out<<<grid4f, blk, 0, stream>>>(outF);
    copy_v0<<<grid4f, blk, 0, stream>>>(v0, outF + NBTC);
    return;
  }

  // Regions: R0=h1/r  R1=Wt(w2)/kf(kept for gn_k)  R2=v
  // R3=Wt(w1)/ao  R4=a/bo/g  R5=w_raw/wd -> Wt(g,o)
  // R6=mix staging/rw.  y (bf16) in d_out v0-slot front half;
  // scal2 + scal4 in its back half.
  u16* W16   = (u16*)d_ws;
  u16* R0 = W16 + 0 * NBTC;
  u16* R1 = W16 + 1 * NBTC;
  u16* R2 = W16 + 2 * NBTC;
  u16* R3 = W16 + 3 * NBTC;
  u16* R4 = W16 + 4 * NBTC;
  u16* R5 = W16 + 5 * NBTC;
  u16* R6 = W16 + 6 * NBTC;
  u16* ws_y = (u16*)(outF + NBTC);          // bf16 y: front half of v0 slot
  float2* scal = (float2*)(ws_y + NBTC);    // kr/br per (b,t,h)
  float4* scal4 = (float4*)(ws_y + NBTC + (size_t)BT * HH * 4);  // pair scalars

  const int gridMix = (BT * CC) / 256;
  dim3 gM(BT / 128, 2048 / 128);            // (32, 16) big GEMMs
  dim3 gH1(BT / 128, 1);                    // skinny N<=128 hidden GEMMs
  dim3 gH2(BT / 128, 2);                    // g-path hidden (N=256)

  // ---- w path: h1 = tanh(xw @ ww_w1) via MFMA (K=2048, N=96 pad 128)
  mix_k<<<gridMix, blk, 0, stream>>>(x, xx_w, R6);
  wt_k<<<dim3(64, 3), blk, 0, stream>>>(ww_w1, R3, 2048, 96, 2048);
  mgemm_k<EPI_H><<<gH1, blk, 0, stream>>>(R6, R3, nullptr, R0,
      BT, 128, 2048, 2048, 2048, 96, 128, 1, nullptr, nullptr, nullptr);
  wt_k<<<dim3(3, 64), blk, 0, stream>>>(ww_w2, R1, 96, 2048, 128);
  mgemm_k<EPI_BIAS_SP><<<gM, blk, 0, stream>>>(R0, R1, nullptr, R5,
      BT, 2048, 128, 128, 128, 0, 0, 0, ww_b, nullptr, nullptr);

  // ---- a path
  mix_k<<<gridMix, blk, 0, stream>>>(x, xx_a, R6);
  wt_k<<<dim3(64, 3), blk, 0, stream>>>(aa_w1, R3, 2048, 96, 2048);
  mgemm_k<EPI_H><<<gH1, blk, 0, stream>>>(R6, R3, nullptr, R0,
      BT, 128, 2048, 2048, 2048, 96, 128, 0, nullptr, nullptr, nullptr);
  wt_k<<<dim3(3, 64), blk, 0, stream>>>(aa_w2, R1, 96, 2048, 128);
  mgemm_k<EPI_BIAS_SIG><<<gM, blk, 0, stream>>>(R0, R1, nullptr, R4,
      BT, 2048, 128, 128, 128, 0, 0, 0, aa_b, nullptr, nullptr);

  // ---- v path
  mix_k<<<gridMix, blk, 0, stream>>>(x, xx_v, R6);
  wt_k<<<dim3(64, 64), blk, 0, stream>>>(W_v, R1, 2048, 2048, 2048);
  mgemm_k<EPI_BF><<<gM, blk, 0, stream>>>(R6, R1, nullptr, R2,
      BT, 2048, 2048, 2048, 2048, 0, 0, 0, nullptr, nullptr, nullptr);
  wt_k<<<dim3(64, 2), blk, 0, stream>>>(vv_w1, R3, 2048, 64, 2048);
  mgemm_k<EPI_H><<<gH1, blk, 0, stream>>>(R6, R3, nullptr, R0,
      BT, 64, 2048, 2048, 2048, 64, 64, 0, nullptr, nullptr, nullptr);
  wt_k<<<dim3(2, 64), blk, 0, stream>>>(vv_w2, R1, 64, 2048, 64);
  mgemm_k<EPI_VMIX><<<gM, blk, 0, stream>>>(R0, R1, nullptr, R2,
      BT, 2048, 64, 64, 64, 0, 0, 0, vv_b, R2, v0);

  // ---- k path
  mix_k<<<gridMix, blk, 0, stream>>>(x, xx_k, R6);
  wt_k<<<dim3(64, 64), blk, 0, stream>>>(W_k, R3, 2048, 2048, 2048);
  mgemm_k<EPI_BF><<<gM, blk, 0, stream>>>(R6, R3, nullptr, R1,
      BT, 2048, 2048, 2048, 2048, 0, 0, 0, nullptr, nullptr, nullptr);

  // ---- r path
  mix_k<<<gridMix, blk, 0, stream>>>(x, xx_r, R6);
  wt_k<<<dim3(64, 64), blk, 0, stream>>>(W_r, R3, 2048, 2048, 2048);
  mgemm_k<EPI_BF><<<gM, blk, 0, stream>>>(R6, R3, nullptr, R0,
      BT, 2048, 2048, 2048, 2048, 0, 0, 0, nullptr, nullptr, nullptr);

  // ---- fused prep+pair-compound: k(R1),a(R4),r(R0),w_raw(R5) ->
  //      ao(R3), bo(R4), kf(R1), wd(R5), rw(R6), scal, scal4
  prep12_k<<<(BB * (TT / 2) * HH) / 4, blk, 0, stream>>>(
      R1, R4, R0, R5, kk_s, ka_s, R3, R4, R1, R5, R6, scal, scal4);

  // ---- recurrence (g=16, 2 steps/iter): rw=R6 wd=R5 kv=R1 v=R2 ao=R3 bo=R4
  rec_k<<<256, blk, 0, stream>>>(R6, R5, R1, R2, R3, R4, scal, scal4, ws_y);

  // ---- g path (R5, R3, R4, R6 dead after rec; R1 kf preserved)
  mix_k<<<gridMix, blk, 0, stream>>>(x, xx_g, R6);
  wt_k<<<dim3(64, 8), blk, 0, stream>>>(gg_w1, R5, 2048, 256, 2048);
  mgemm_k<EPI_H><<<gH2, blk, 0, stream>>>(R6, R5, nullptr, R3,
      BT, 256, 2048, 2048, 2048, 256, 256, 2, nullptr, nullptr, nullptr);
  wt_k<<<dim3(8, 64), blk, 0, stream>>>(gg_w2, R5, 256, 2048, 256);
  mgemm_k<EPI_BF><<<gM, blk, 0, stream>>>(R3, R5, nullptr, R4,
      BT, 2048, 256, 256, 256, 0, 0, 0, nullptr, nullptr, nullptr);

  // ---- groupnorm + bonus + gate (in place on y; k=R1 kf intact)
  gn_k<<<BT * HH / 4, blk, 0, stream>>>(ws_y, R0, R1, R2, R4,
                                        rk_s, gn_w, gn_b);

  // ---- final projection y @ W_o -> fp32 output 0
  wt_k<<<dim3(64, 64), blk, 0, stream>>>(W_o, R5, 2048, 2048, 2048);
  mgemm_k<EPI_F32><<<gM, blk, 0, stream>>>(ws_y, R5, outF, nullptr,
      BT, 2048, 2048, 2048, 2048, 0, 0, 0, nullptr, nullptr, nullptr);

  // ---- v0 passthrough (overwrites y scratch + scal, last)
  copy_v0<<<grid4f, blk, 0, stream>>>(v0, outF + NBTC);
}

// Round 19
// 820.151 us; speedup vs baseline: 1.0573x; 1.0573x over previous
//
#include <hip/hip_runtime.h>
#include <hip/hip_bf16.h>
#include <math.h>

typedef unsigned short u16;
typedef __attribute__((ext_vector_type(4))) unsigned short us4;
typedef __attribute__((ext_vector_type(8))) unsigned short us8;
typedef __attribute__((ext_vector_type(8))) short s8v;   // mfma bf16 operand (4 VGPRs)
typedef __attribute__((ext_vector_type(4))) float f4v;   // mfma accum

#define BB 2
#define TT 1024
#define CC 2048
#define HH 32
#define BT (BB*TT)

// R17 structure (best passing: 805us) + DPP butterfly in rec_k.
// Inputs/outputs fp32. ws intermediates bf16: 7 regions x NBTC u16.
// Skinny w1 projections: SIMT K-split + reduce (R18 showed MFMA there is
// launch-width-limited and slower). rec_k = R13 pair form with butterfly
// levels 1,2 as DPP quad_perm VALU adds (xor1=0xB1, xor2=0x4E) instead of
// ds_swizzle -- halves DS ops on the serial chain.

__device__ __forceinline__ float bf2f(u16 u) {
  return __uint_as_float(((unsigned int)u) << 16);
}
__device__ __forceinline__ u16 f2bf(float f) {
  unsigned int x = __float_as_uint(f);
  x += 0x7fffu + ((x >> 16) & 1u);
  return (u16)(x >> 16);
}

__device__ __forceinline__ void gload16(const u16* g, u16* l) {
  __builtin_amdgcn_global_load_lds(
      (const __attribute__((address_space(1))) void*)g,
      (__attribute__((address_space(3))) void*)l, 16, 0, 0);
}

// DPP cross-lane add: x + x[lane ^ k] for k=1 (ctrl 0xB1), k=2 (ctrl 0x4E).
template<int CTRL>
__device__ __forceinline__ float dpp_add(float x) {
  int t = __builtin_amdgcn_update_dpp(0, __float_as_int(x), CTRL, 0xF, 0xF,
                                      true);
  return x + __int_as_float(t);
}

// ---------------------------------------------------------------- mix kernel
__global__ __launch_bounds__(256)
void mix_k(const float* __restrict__ x, const float* __restrict__ s,
           u16* __restrict__ out) {
  int idx = blockIdx.x * 256 + threadIdx.x;       // over BT*C
  int c = idx & (CC - 1);
  int t = (idx >> 11) & (TT - 1);
  float xv = x[idx];
  float xp = (t == 0) ? 0.f : x[idx - CC];
  out[idx] = f2bf(xv + (xp - xv) * s[c]);
}

// ---------------------------------------------------------------- weight cvt-transpose
__global__ __launch_bounds__(256)
void wt_k(const float* __restrict__ W, u16* __restrict__ Wt, int K, int N,
          int Kp) {
  __shared__ u16 tile[32][36];
  const int k0 = blockIdx.x * 32, n0 = blockIdx.y * 32;
  const int tid = threadIdx.x;
  const int r = tid >> 3, c4 = (tid & 7) << 2;
  float4 v = *(const float4*)(W + (size_t)(k0 + r) * N + n0 + c4);
  tile[r][c4 + 0] = f2bf(v.x); tile[r][c4 + 1] = f2bf(v.y);
  tile[r][c4 + 2] = f2bf(v.z); tile[r][c4 + 3] = f2bf(v.w);
  __syncthreads();
  ushort4 o;
  o.x = tile[c4 + 0][r]; o.y = tile[c4 + 1][r];
  o.z = tile[c4 + 2][r]; o.w = tile[c4 + 3][r];
  *(ushort4*)(Wt + (size_t)(n0 + r) * Kp + k0 + c4) = o;
}

// ---------------------------------------------------------------- MFMA GEMM
// C[M,N] = A[M,lda](bf16) * Bt[N,ldb](bf16), fp32 accum. 128x128, BK=64,
// global_load_lds + both-sides XOR swizzle (R13).
enum { EPI_BF = 0, EPI_F32 = 1, EPI_BIAS_SP = 2, EPI_BIAS_SIG = 3,
       EPI_VMIX = 4 };

template<int EPI>
__global__ __launch_bounds__(256)
void mgemm_k(const u16* __restrict__ A, const u16* __restrict__ Bt,
             float* __restrict__ outF, u16* __restrict__ outB,
             int M, int N, int K, int lda, int ldb,
             const float* __restrict__ bias, const u16* __restrict__ p1,
             const float* __restrict__ p2)
{
  __shared__ alignas(16) u16 As[128 * 64];
  __shared__ alignas(16) u16 Bs[128 * 64];
  const int m0 = blockIdx.x * 128;
  const int n0 = blockIdx.y * 128;
  const int tid = threadIdx.x;
  const int lane = tid & 63;
  const int wid = tid >> 6;
  const int wr = wid >> 1, wc = wid & 1;
  f4v acc[4][4];
  #pragma unroll
  for (int i = 0; i < 4; ++i)
    #pragma unroll
    for (int j = 0; j < 4; ++j) acc[i][j] = f4v{0.f, 0.f, 0.f, 0.f};

  const int l15 = lane & 15;
  const int lq = lane >> 4;
  const int nkt = K >> 6;
  for (int kt = 0; kt < nkt; ++kt) {
    const int k0 = kt << 6;
    __syncthreads();
    #pragma unroll
    for (int a = 0; a < 4; ++a) {
      const int blkU = (wid * 4 + a) * 64;
      const int U = blkU + lane;
      const int row = U >> 3;
      const int u = U & 7;
      const int col = ((u ^ (row & 7)) << 3);
      gload16(A  + (size_t)(m0 + row) * lda + k0 + col, &As[blkU * 8]);
      gload16(Bt + (size_t)(n0 + row) * ldb + k0 + col, &Bs[blkU * 8]);
    }
    __syncthreads();
    #pragma unroll
    for (int h = 0; h < 2; ++h) {
      s8v af[4], bfr[4];
      #pragma unroll
      for (int i = 0; i < 4; ++i) {
        const int row = wr * 64 + i * 16 + l15;
        const int u = (h * 4 + lq) ^ (row & 7);
        af[i] = *(const s8v*)&As[row * 64 + u * 8];
      }
      #pragma unroll
      for (int j = 0; j < 4; ++j) {
        const int row = wc * 64 + j * 16 + l15;
        const int u = (h * 4 + lq) ^ (row & 7);
        bfr[j] = *(const s8v*)&Bs[row * 64 + u * 8];
      }
      #pragma unroll
      for (int i = 0; i < 4; ++i)
        #pragma unroll
        for (int j = 0; j < 4; ++j)
          acc[i][j] = __builtin_amdgcn_mfma_f32_16x16x32_bf16(af[i], bfr[j],
                                                              acc[i][j],
                                                              0, 0, 0);
    }
  }
  const int rbase = m0 + wr * 64 + (lq << 2);
  const int cbase = n0 + wc * 64 + l15;
  #pragma unroll
  for (int i = 0; i < 4; ++i) {
    #pragma unroll
    for (int j = 0; j < 4; ++j) {
      f4v c = acc[i][j];
      const int col = cbase + j * 16;
      #pragma unroll
      for (int q = 0; q < 4; ++q) {
        const int row = rbase + i * 16 + q;
        const size_t idx = (size_t)row * N + col;
        const float r = c[q];
        if (EPI == EPI_BF) {
          outB[idx] = f2bf(r);
        } else if (EPI == EPI_F32) {
          outF[idx] = r;
        } else if (EPI == EPI_BIAS_SP) {
          float u = bias[col] + r;
          float z = -u;
          float sp = fmaxf(z, 0.f) + log1pf(expf(-fabsf(z)));
          outB[idx] = f2bf(-sp - 0.5f);
        } else if (EPI == EPI_BIAS_SIG) {
          float u = bias[col] + r;
          outB[idx] = f2bf(1.f / (1.f + expf(-u)));
        } else if (EPI == EPI_VMIX) {
          float u = bias[col] + r;
          float sg = 1.f / (1.f + expf(-u));
          float v = bf2f(p1[idx]);
          float v0v = p2[idx];
          outB[idx] = f2bf(v + (v0v - v) * sg);
        }
      }
    }
  }
}

// ---------------------------------------------------------------- SIMT GEMM (skinny w1 paths)
__global__ __launch_bounds__(256)
void gemm_part_k(const u16* __restrict__ A, const float* __restrict__ W,
                 float* __restrict__ outF, int M, int N, int K, int kchunk,
                 int NP)
{
  __shared__ alignas(16) float As[16][68];
  __shared__ alignas(16) float Bs[16][68];
  const int m0 = blockIdx.x * 64;
  const int n0 = blockIdx.y * 64;
  const int kz = blockIdx.z;
  const int k0base = kz * kchunk;
  const int tid = threadIdx.x;
  const int tx = tid & 15, ty = tid >> 4;
  float acc[4][4] = {{0.f}};
  const int a_m = tid >> 2;
  const int a_k = (tid & 3) << 2;
  const int b_k = tid >> 4;
  const int b_n = (tid & 15) << 2;
  const int niters = kchunk >> 4;
  for (int it = 0; it < niters; ++it) {
    const int k0 = k0base + (it << 4);
    float4 av;
    {
      ushort4 u = *(const ushort4*)(A + (size_t)(m0 + a_m) * K + (k0 + a_k));
      av = make_float4(bf2f(u.x), bf2f(u.y), bf2f(u.z), bf2f(u.w));
    }
    float4 bv;
    {
      int gn = n0 + b_n;
      const float* wp = W + (size_t)(k0 + b_k) * N + gn;
      if (gn + 3 < N) {
        bv = *(const float4*)wp;
      } else {
        bv.x = (gn + 0 < N) ? wp[0] : 0.f;
        bv.y = (gn + 1 < N) ? wp[1] : 0.f;
        bv.z = (gn + 2 < N) ? wp[2] : 0.f;
        bv.w = (gn + 3 < N) ? wp[3] : 0.f;
      }
    }
    __syncthreads();
    As[a_k + 0][a_m] = av.x; As[a_k + 1][a_m] = av.y;
    As[a_k + 2][a_m] = av.z; As[a_k + 3][a_m] = av.w;
    Bs[b_k][b_n + 0] = bv.x; Bs[b_k][b_n + 1] = bv.y;
    Bs[b_k][b_n + 2] = bv.z; Bs[b_k][b_n + 3] = bv.w;
    __syncthreads();
    #pragma unroll
    for (int kk = 0; kk < 16; ++kk) {
      float4 a4 = *(const float4*)&As[kk][ty << 2];
      float4 b4 = *(const float4*)&Bs[kk][tx << 2];
      float ar[4] = {a4.x, a4.y, a4.z, a4.w};
      float br[4] = {b4.x, b4.y, b4.z, b4.w};
      #pragma unroll
      for (int i = 0; i < 4; ++i)
        #pragma unroll
        for (int j = 0; j < 4; ++j)
          acc[i][j] = fmaf(ar[i], br[j], acc[i][j]);
    }
  }
  #pragma unroll
  for (int i = 0; i < 4; ++i) {
    int gm = m0 + (ty << 2) + i;
    #pragma unroll
    for (int j = 0; j < 4; ++j) {
      int gn = n0 + (tx << 2) + j;
      if (gn >= N) continue;
      outF[((size_t)kz * M + gm) * NP + gn] = acc[i][j];
    }
  }
}

// ---------------------------------------------------------------- K-split reduce
__global__ __launch_bounds__(256)
void reduce_k(const float* __restrict__ part, u16* __restrict__ out,
              int M, int D, int NP, int nz, int act, int Dp)
{
  int idx = blockIdx.x * 256 + threadIdx.x;
  if (idx >= M * Dp) return;
  int t = idx / Dp, n = idx - t * Dp;
  float s = 0.f;
  if (n < D) {
    for (int z = 0; z < nz; ++z) s += part[((size_t)z * M + t) * NP + n];
    if (act == 1) s = tanhf(s);
    else if (act == 2) s = 1.f / (1.f + expf(-s));
  }
  out[idx] = f2bf(s);
}

// ---------------------------------------------------------------- fused pair prep
__global__ __launch_bounds__(256)
void prep12_k(const u16* __restrict__ k_in, const u16* __restrict__ a_in,
              const u16* __restrict__ r_in, const u16* __restrict__ w_in,
              const float* __restrict__ kk_s, const float* __restrict__ ka_s,
              u16* __restrict__ ao_out, u16* __restrict__ bo_out,
              u16* __restrict__ k_out, u16* __restrict__ wd_out,
              u16* __restrict__ rw_out, float2* __restrict__ scal,
              float4* __restrict__ scal4)
{
  const int tid = threadIdx.x;
  const int lane = tid & 63;
  const int hpidx = blockIdx.x * 4 + (tid >> 6);  // (b*T/2+tp)*H + h
  const int h = hpidx & (HH - 1);
  const int btp = hpidx >> 5;
  const int tp = btp & (TT / 2 - 1);
  const int b = btp >> 9;                          // TT/2 = 512
  const int c = (h << 6) + lane;
  const size_t be = ((size_t)(b * TT + 2 * tp)) * CC + (h << 6) + lane;
  const size_t bod = be + CC;
  const float ks = kk_s[c], kas = ka_s[c];
  const float k1 = bf2f(k_in[be]),  k2 = bf2f(k_in[bod]);
  const float a1 = bf2f(a_in[be]),  a2 = bf2f(a_in[bod]);
  const float r1 = bf2f(r_in[be]),  r2 = bf2f(r_in[bod]);
  const float wraw1 = bf2f(w_in[be]), wraw2 = bf2f(w_in[bod]);
  float kk1 = k1 * ks, kk2 = k2 * ks;
  float ss1 = kk1 * kk1, ss2 = kk2 * kk2;
  #pragma unroll
  for (int off = 32; off; off >>= 1) {
    ss1 += __shfl_xor(ss1, off, 64);
    ss2 += __shfl_xor(ss2, off, 64);
  }
  const float kkn1 = kk1 / fmaxf(sqrtf(ss1), 1e-12f);
  const float kkn2 = kk2 / fmaxf(sqrtf(ss2), 1e-12f);
  const float kf1 = k1 * (1.f + (a1 - 1.f) * kas);
  const float kf2 = k2 * (1.f + (a2 - 1.f) * kas);
  const float wd1 = expf(-expf(wraw1));
  const float wd2 = expf(-expf(wraw2));
  const float ao1 = -kkn1, ao2 = -kkn2;
  const float bo1 = kkn1 * a1, bo2 = kkn2 * a2;
  const float rw1 = wd1 * r1, rw2 = wd2 * r2;
  float kr1 = kf1 * r1, br1 = bo1 * r1;
  float kr2 = kf2 * r2, br2 = bo2 * r2;
  float cba = bo1 * ao2, ckb = kf1 * ao2;
  float crb = bo1 * rw2, crk = kf1 * rw2;
  #pragma unroll
  for (int off = 32; off; off >>= 1) {
    kr1 += __shfl_xor(kr1, off, 64);  br1 += __shfl_xor(br1, off, 64);
    kr2 += __shfl_xor(kr2, off, 64);  br2 += __shfl_xor(br2, off, 64);
    cba += __shfl_xor(cba, off, 64);  ckb += __shfl_xor(ckb, off, 64);
    crb += __shfl_xor(crb, off, 64);  crk += __shfl_xor(crk, off, 64);
  }
  ao_out[be]  = f2bf(ao1);
  ao_out[bod] = f2bf(wd1 * ao2);
  bo_out[be]  = f2bf(bo1 * wd2);
  bo_out[bod] = f2bf(bo2);
  k_out[be]   = f2bf(kf1);
  k_out[bod]  = f2bf(kf2);
  wd_out[be]  = f2bf(wd1 * wd2);
  wd_out[bod] = f2bf(kf1 * wd2);
  rw_out[be]  = f2bf(rw1);
  rw_out[bod] = f2bf(wd1 * rw2);
  if (lane == 0) {
    const int se = (b * TT + 2 * tp) * HH + h;
    scal[se]      = make_float2(kr1, br1);
    scal[se + HH] = make_float2(kr2, br2);
    scal4[hpidx]  = make_float4(cba, ckb, crb, crk);
  }
}

// ---------------------------------------------------------------- RWKV7 recurrence
// g=16 pair form; butterfly levels 1,2 via DPP quad_perm (VALU), 4,8 via shfl.
__global__ __launch_bounds__(256)
void rec_k(const u16* __restrict__ rw, const u16* __restrict__ wd,
           const u16* __restrict__ kv, const u16* __restrict__ v,
           const u16* __restrict__ ao, const u16* __restrict__ bo,
           const float2* __restrict__ scal, const float4* __restrict__ scal4,
           u16* __restrict__ y)
{
  const int gw = blockIdx.x * 4 + (threadIdx.x >> 6);   // 0..1023
  const int lane = threadIdx.x & 63;
  const int sub = lane & 15;
  const int grp = lane >> 4;
  const int bh = gw >> 4;
  const int rblk = gw & 15;
  const int i = rblk * 4 + grp;
  const int b = bh >> 5, h = bh & (HH - 1);
  const size_t base0 = ((size_t)b * TT) * CC + (h << 6);
  const size_t vecb = base0 + (sub << 2);
  const size_t vb   = base0 + i;
  const int sbase = b * TT * HH + h;
  const int pbase = b * (TT / 2) * HH + h;
  float s0 = 0.f, s1 = 0.f, s2 = 0.f, s3 = 0.f;

  us4 W12, KW1, AO1, WA2, BW1, BO2, RW1, WR2, K2;
  float V1, V2; float2 SE, SO; float4 S4;
#define PLOAD(TP) do {                                                  \
    const size_t be_ = vecb + (size_t)(2 * (TP)) * CC;                  \
    const size_t bo_ = be_ + CC;                                        \
    W12 = *(const us4*)(wd + be_);  KW1 = *(const us4*)(wd + bo_);      \
    AO1 = *(const us4*)(ao + be_);  WA2 = *(const us4*)(ao + bo_);      \
    BW1 = *(const us4*)(bo + be_);  BO2 = *(const us4*)(bo + bo_);      \
    RW1 = *(const us4*)(rw + be_);  WR2 = *(const us4*)(rw + bo_);      \
    K2  = *(const us4*)(kv + bo_);                                      \
    V1 = bf2f(v[vb + (size_t)(2 * (TP)) * CC]);                         \
    V2 = bf2f(v[vb + (size_t)(2 * (TP) + 1) * CC]);                     \
    SE = scal[sbase + (2 * (TP)) * HH];                                 \
    SO = scal[sbase + (2 * (TP) + 1) * HH];                             \
    S4 = scal4[pbase + (TP) * HH];                                      \
  } while (0)

  PLOAD(0);
  for (int tp = 0; tp < TT / 2; ++tp) {
    const float w0 = bf2f(W12[0]), w1 = bf2f(W12[1]),
                w2 = bf2f(W12[2]), w3 = bf2f(W12[3]);
    const float kw0 = bf2f(KW1[0]), kw1_ = bf2f(KW1[1]),
                kw2 = bf2f(KW1[2]), kw3 = bf2f(KW1[3]);
    const float a0 = bf2f(AO1[0]), a1 = bf2f(AO1[1]),
                a2 = bf2f(AO1[2]), a3 = bf2f(AO1[3]);
    const float x0 = bf2f(WA2[0]), x1 = bf2f(WA2[1]),
                x2 = bf2f(WA2[2]), x3 = bf2f(WA2[3]);
    const float bw0 = bf2f(BW1[0]), bw1_ = bf2f(BW1[1]),
                bw2 = bf2f(BW1[2]), bw3 = bf2f(BW1[3]);
    const float b0 = bf2f(BO2[0]), b1 = bf2f(BO2[1]),
                b2 = bf2f(BO2[2]), b3 = bf2f(BO2[3]);
    const float e0 = bf2f(RW1[0]), e1 = bf2f(RW1[1]),
                e2 = bf2f(RW1[2]), e3 = bf2f(RW1[3]);
    const float f0 = bf2f(WR2[0]), f1 = bf2f(WR2[1]),
                f2 = bf2f(WR2[2]), f3 = bf2f(WR2[3]);
    const float k0 = bf2f(K2[0]), k1 = bf2f(K2[1]),
                k2 = bf2f(K2[2]), k3 = bf2f(K2[3]);
    const float v1c = V1, v2c = V2;
    const float kr1 = SE.x, br1 = SE.y, kr2 = SO.x, br2 = SO.y;
    const float cba = S4.x, ckb = S4.y, crb = S4.z, crk = S4.w;
    if (tp + 1 < TT / 2) PLOAD(tp + 1);
    float u1 = fmaf(s3, a3, fmaf(s2, a2, fmaf(s1, a1, s0 * a0)));
    float u2 = fmaf(s3, x3, fmaf(s2, x2, fmaf(s1, x1, s0 * x0)));
    float q1 = fmaf(s3, e3, fmaf(s2, e2, fmaf(s1, e1, s0 * e0)));
    float q2 = fmaf(s3, f3, fmaf(s2, f2, fmaf(s1, f1, s0 * f0)));
    // levels 1,2: DPP quad_perm (VALU); levels 4,8: ds shfl
    u1 = dpp_add<0xB1>(u1);  u2 = dpp_add<0xB1>(u2);
    q1 = dpp_add<0xB1>(q1);  q2 = dpp_add<0xB1>(q2);
    u1 = dpp_add<0x4E>(u1);  u2 = dpp_add<0x4E>(u2);
    q1 = dpp_add<0x4E>(q1);  q2 = dpp_add<0x4E>(q2);
    u1 += __shfl_xor(u1, 4, 64);  u2 += __shfl_xor(u2, 4, 64);
    q1 += __shfl_xor(q1, 4, 64);  q2 += __shfl_xor(q2, 4, 64);
    u1 += __shfl_xor(u1, 8, 64);  u2 += __shfl_xor(u2, 8, 64);
    q1 += __shfl_xor(q1, 8, 64);  q2 += __shfl_xor(q2, 8, 64);
    const float sac = fmaf(ckb, v1c, fmaf(cba, u1, u2));
    const float y1 = fmaf(br1, u1, fmaf(kr1, v1c, q1));
    const float y2 = fmaf(br2, sac, fmaf(kr2, v2c,
                       fmaf(crb, u1, fmaf(crk, v1c, q2))));
    s0 = fmaf(v2c, k0, fmaf(v1c, kw0, fmaf(sac, b0, fmaf(u1, bw0, s0 * w0))));
    s1 = fmaf(v2c, k1, fmaf(v1c, kw1_, fmaf(sac, b1, fmaf(u1, bw1_, s1 * w1))));
    s2 = fmaf(v2c, k2, fmaf(v1c, kw2, fmaf(sac, b2, fmaf(u1, bw2, s2 * w2))));
    s3 = fmaf(v2c, k3, fmaf(v1c, kw3, fmaf(sac, b3, fmaf(u1, bw3, s3 * w3))));
    if (sub == 0) {
      y[vb + (size_t)(2 * tp) * CC] = f2bf(y1);
      y[vb + (size_t)(2 * tp + 1) * CC] = f2bf(y2);
    }
  }
#undef PLOAD
}

// ---------------------------------------------------------------- GroupNorm + bonus + gate
__global__ __launch_bounds__(256)
void gn_k(u16* __restrict__ y, const u16* __restrict__ r,
          const u16* __restrict__ k, const u16* __restrict__ v,
          const u16* __restrict__ g, const float* __restrict__ rk_s,
          const float* __restrict__ gn_w, const float* __restrict__ gn_b)
{
  int tid = threadIdx.x, lane = tid & 63, wv = tid >> 6;
  int hidx = blockIdx.x * 4 + wv;
  int h = hidx & (HH - 1);
  int c = (h << 6) + lane;
  size_t base = ((size_t)hidx << 6) + lane;
  float yv = bf2f(y[base]), rv = bf2f(r[base]), kv = bf2f(k[base]);
  float vv = bf2f(v[base]), gv = bf2f(g[base]);
  float bsum = rv * kv * rk_s[c];
  float s1 = yv, s2 = yv * yv;
  for (int off = 32; off; off >>= 1) {
    s1 += __shfl_xor(s1, off, 64);
    s2 += __shfl_xor(s2, off, 64);
    bsum += __shfl_xor(bsum, off, 64);
  }
  float mu = s1 * (1.f / 64.f);
  float var = s2 * (1.f / 64.f) - mu * mu;
  float rstd = rsqrtf(var + 0.00064f);
  float z = (yv - mu) * rstd * gn_w[c] + gn_b[c];
  y[base] = f2bf((z + bsum * vv) * gv);
}

// ---------------------------------------------------------------- helpers
__global__ __launch_bounds__(256)
void copy_v0(const float* __restrict__ v0, float* __restrict__ out) {
  int idx = blockIdx.x * 256 + threadIdx.x;
  ((float4*)out)[idx] = ((const float4*)v0)[idx];
}

__global__ __launch_bounds__(256)
void zero_out(float* __restrict__ out) {
  int idx = blockIdx.x * 256 + threadIdx.x;
  ((float4*)out)[idx] = make_float4(0.f, 0.f, 0.f, 0.f);
}

// ----------------------------------------------------------------
extern "C" void kernel_launch(void* const* d_in, const int* in_sizes, int n_in,
                              void* d_out, int out_size, void* d_ws, size_t ws_size,
                              hipStream_t stream) {
  (void)n_in; (void)out_size;
  const bool dictOrder = (in_sizes[9] == CC);
  int IX[28];
  if (dictOrder) {
    const int m[28] = {0,1,2,3,4,5,6,7, 8,13,14, 9,15,16, 10,17,18, 19,20,
                       11,12,21, 22,23,24,25, 26,27};
    for (int i = 0; i < 28; ++i) IX[i] = m[i];
  } else {
    for (int i = 0; i < 28; ++i) IX[i] = i;
  }
  const float* x     = (const float*)d_in[IX[0]];
  const float* v0    = (const float*)d_in[IX[1]];
  const float* xx_r  = (const float*)d_in[IX[2]];
  const float* xx_w  = (const float*)d_in[IX[3]];
  const float* xx_k  = (const float*)d_in[IX[4]];
  const float* xx_v  = (const float*)d_in[IX[5]];
  const float* xx_a  = (const float*)d_in[IX[6]];
  const float* xx_g  = (const float*)d_in[IX[7]];
  const float* ww_b  = (const float*)d_in[IX[8]];
  const float* ww_w1 = (const float*)d_in[IX[9]];
  const float* ww_w2 = (const float*)d_in[IX[10]];
  const float* aa_b  = (const float*)d_in[IX[11]];
  const float* aa_w1 = (const float*)d_in[IX[12]];
  const float* aa_w2 = (const float*)d_in[IX[13]];
  const float* vv_b  = (const float*)d_in[IX[14]];
  const float* vv_w1 = (const float*)d_in[IX[15]];
  const float* vv_w2 = (const float*)d_in[IX[16]];
  const float* gg_w1 = (const float*)d_in[IX[17]];
  const float* gg_w2 = (const float*)d_in[IX[18]];
  const float* kk_s  = (const float*)d_in[IX[19]];
  const float* ka_s  = (const float*)d_in[IX[20]];
  const float* rk_s  = (const float*)d_in[IX[21]];
  const float* W_r   = (const float*)d_in[IX[22]];
  const float* W_k   = (const float*)d_in[IX[23]];
  const float* W_v   = (const float*)d_in[IX[24]];
  const float* W_o   = (const float*)d_in[IX[25]];
  const float* gn_w  = (const float*)d_in[IX[26]];
  const float* gn_b  = (const float*)d_in[IX[27]];

  const size_t NBTC = (size_t)BT * CC;
  dim3 blk(256);
  const int grid4f = (int)(NBTC / 4 / 256);

  const size_t WS_NEED = 7 * NBTC * sizeof(u16);
  float* outF = (float*)d_out;
  if (ws_size < WS_NEED || d_ws == nullptr) {
    zero_out<<<grid4f, blk, 0, stream>>>(outF);
    copy_v0<<<grid4f, blk, 0, stream>>>(v0, outF + NBTC);
    return;
  }

  // Regions: R0=h1/r  R1=Wt(w2)/kf(kept for gn_k)  R2=v
  // R3=partY/Wt/ao  R4=a/bo/g  R5=w_raw/wd -> partG/Wt(g,o)
  // R6=mix staging/rw.  y (bf16) in d_out v0-slot front half;
  // scal2 + scal4 in its back half.
  u16* W16   = (u16*)d_ws;
  u16* R0 = W16 + 0 * NBTC;
  u16* R1 = W16 + 1 * NBTC;
  u16* R2 = W16 + 2 * NBTC;
  u16* R3 = W16 + 3 * NBTC;
  u16* R4 = W16 + 4 * NBTC;
  u16* R5 = W16 + 5 * NBTC;
  u16* R6 = W16 + 6 * NBTC;
  float* partY = (float*)R3;
  float* partG = (float*)R5;
  u16* ws_y = (u16*)(outF + NBTC);          // bf16 y: front half of v0 slot
  float2* scal = (float2*)(ws_y + NBTC);    // kr/br per (b,t,h)
  float4* scal4 = (float4*)(ws_y + NBTC + (size_t)BT * HH * 4);  // pair scalars

  const int gridMix = (BT * CC) / 256;
  dim3 gM(BT / 128, 2048 / 128);            // (32, 16)

  // ---- w path (K=96 padded to 128)
  mix_k<<<gridMix, blk, 0, stream>>>(x, xx_w, R6);
  gemm_part_k<<<dim3(32, 2, 8), blk, 0, stream>>>(R6, ww_w1, partY,
      BT, 96, 2048, 256, 128);
  reduce_k<<<(BT * 128) / 256, blk, 0, stream>>>(partY, R0, BT, 96, 128, 8, 1, 128);
  wt_k<<<dim3(3, 64), blk, 0, stream>>>(ww_w2, R1, 96, 2048, 128);
  mgemm_k<EPI_BIAS_SP><<<gM, blk, 0, stream>>>(R0, R1, nullptr, R5,
      BT, 2048, 128, 128, 128, ww_b, nullptr, nullptr);

  // ---- a path (K=96 padded to 128)
  mix_k<<<gridMix, blk, 0, stream>>>(x, xx_a, R6);
  gemm_part_k<<<dim3(32, 2, 8), blk, 0, stream>>>(R6, aa_w1, partY,
      BT, 96, 2048, 256, 128);
  reduce_k<<<(BT * 128) / 256, blk, 0, stream>>>(partY, R0, BT, 96, 128, 8, 0, 128);
  wt_k<<<dim3(3, 64), blk, 0, stream>>>(aa_w2, R1, 96, 2048, 128);
  mgemm_k<EPI_BIAS_SIG><<<gM, blk, 0, stream>>>(R0, R1, nullptr, R4,
      BT, 2048, 128, 128, 128, aa_b, nullptr, nullptr);

  // ---- v path
  mix_k<<<gridMix, blk, 0, stream>>>(x, xx_v, R6);
  wt_k<<<dim3(64, 64), blk, 0, stream>>>(W_v, R1, 2048, 2048, 2048);
  mgemm_k<EPI_BF><<<gM, blk, 0, stream>>>(R6, R1, nullptr, R2,
      BT, 2048, 2048, 2048, 2048, nullptr, nullptr, nullptr);
  gemm_part_k<<<dim3(32, 1, 8), blk, 0, stream>>>(R6, vv_w1, partY,
      BT, 64, 2048, 256, 64);
  reduce_k<<<(BT * 64) / 256, blk, 0, stream>>>(partY, R0, BT, 64, 64, 8, 0, 64);
  wt_k<<<dim3(2, 64), blk, 0, stream>>>(vv_w2, R1, 64, 2048, 64);
  mgemm_k<EPI_VMIX><<<gM, blk, 0, stream>>>(R0, R1, nullptr, R2,
      BT, 2048, 64, 64, 64, vv_b, R2, v0);

  // ---- k path
  mix_k<<<gridMix, blk, 0, stream>>>(x, xx_k, R6);
  wt_k<<<dim3(64, 64), blk, 0, stream>>>(W_k, R3, 2048, 2048, 2048);
  mgemm_k<EPI_BF><<<gM, blk, 0, stream>>>(R6, R3, nullptr, R1,
      BT, 2048, 2048, 2048, 2048, nullptr, nullptr, nullptr);

  // ---- r path
  mix_k<<<gridMix, blk, 0, stream>>>(x, xx_r, R6);
  wt_k<<<dim3(64, 64), blk, 0, stream>>>(W_r, R3, 2048, 2048, 2048);
  mgemm_k<EPI_BF><<<gM, blk, 0, stream>>>(R6, R3, nullptr, R0,
      BT, 2048, 2048, 2048, 2048, nullptr, nullptr, nullptr);

  // ---- fused prep+pair-compound: k(R1),a(R4),r(R0),w_raw(R5) ->
  //      ao(R3), bo(R4), kf(R1), wd(R5), rw(R6), scal, scal4
  prep12_k<<<(BB * (TT / 2) * HH) / 4, blk, 0, stream>>>(
      R1, R4, R0, R5, kk_s, ka_s, R3, R4, R1, R5, R6, scal, scal4);

  // ---- recurrence (g=16, 2 steps/iter, DPP butterfly levels 1-2)
  rec_k<<<256, blk, 0, stream>>>(R6, R5, R1, R2, R3, R4, scal, scal4, ws_y);

  // ---- g path (R5, R3, R4, R6 dead after rec; R1 kf preserved)
  mix_k<<<gridMix, blk, 0, stream>>>(x, xx_g, R6);
  gemm_part_k<<<dim3(32, 4, 2), blk, 0, stream>>>(R6, gg_w1, partG,
      BT, 256, 2048, 1024, 256);
  reduce_k<<<(BT * 256) / 256, blk, 0, stream>>>(partG, R3, BT, 256, 256, 2, 2, 256);
  wt_k<<<dim3(8, 64), blk, 0, stream>>>(gg_w2, R5, 256, 2048, 256);
  mgemm_k<EPI_BF><<<gM, blk, 0, stream>>>(R3, R5, nullptr, R4,
      BT, 2048, 256, 256, 256, nullptr, nullptr, nullptr);

  // ---- groupnorm + bonus + gate (in place on y; k=R1 kf intact)
  gn_k<<<BT * HH / 4, blk, 0, stream>>>(ws_y, R0, R1, R2, R4,
                                        rk_s, gn_w, gn_b);

  // ---- final projection y @ W_o -> fp32 output 0
  wt_k<<<dim3(64, 64), blk, 0, stream>>>(W_o, R5, 2048, 2048, 2048);
  mgemm_k<EPI_F32><<<gM, blk, 0, stream>>>(ws_y, R5, outF, nullptr,
      BT, 2048, 2048, 2048, 2048, nullptr, nullptr, nullptr);

  // ---- v0 passthrough (overwrites y scratch + scal, last)
  copy_v0<<<grid4f, blk, 0, stream>>>(v0, outF + NBTC);
}

// Round 20
// 801.212 us; speedup vs baseline: 1.0823x; 1.0236x over previous
//
#include <hip/hip_runtime.h>
#include <hip/hip_bf16.h>
#include <math.h>

typedef unsigned short u16;
typedef __attribute__((ext_vector_type(4))) unsigned short us4;
typedef __attribute__((ext_vector_type(8))) unsigned short us8;
typedef __attribute__((ext_vector_type(8))) short s8v;   // mfma bf16 operand (4 VGPRs)
typedef __attribute__((ext_vector_type(4))) float f4v;   // mfma accum

#define BB 2
#define TT 1024
#define CC 2048
#define HH 32
#define BT (BB*TT)

// R17 structure (best passing: 805us) with float4-vectorized mix_k.
// Inputs/outputs fp32. ws intermediates bf16: 7 regions x NBTC u16.
// Skinny w1 projections: SIMT K-split + reduce. rec_k = R13/R17 pair form
// (g=16, 2 steps/iter, 4-level shfl butterfly of 4 interleaved reductions).

__device__ __forceinline__ float bf2f(u16 u) {
  return __uint_as_float(((unsigned int)u) << 16);
}
__device__ __forceinline__ u16 f2bf(float f) {
  unsigned int x = __float_as_uint(f);
  x += 0x7fffu + ((x >> 16) & 1u);
  return (u16)(x >> 16);
}

__device__ __forceinline__ void gload16(const u16* g, u16* l) {
  __builtin_amdgcn_global_load_lds(
      (const __attribute__((address_space(1))) void*)g,
      (__attribute__((address_space(3))) void*)l, 16, 0, 0);
}

// ---------------------------------------------------------------- mix kernel
// float4-vectorized: 4 elems/thread (C % 4 == 0, so c-block and t are
// uniform within a granule).
__global__ __launch_bounds__(256)
void mix_k(const float* __restrict__ x, const float* __restrict__ s,
           u16* __restrict__ out) {
  int idx = blockIdx.x * 256 + threadIdx.x;       // over BT*C/4 granules
  int e = idx << 2;
  int c = e & (CC - 1);
  int t = (e >> 11) & (TT - 1);
  float4 xv = *(const float4*)(x + e);
  float4 sv = *(const float4*)(s + c);
  float4 xp = make_float4(0.f, 0.f, 0.f, 0.f);
  if (t != 0) xp = *(const float4*)(x + e - CC);
  ushort4 o;
  o.x = f2bf(xv.x + (xp.x - xv.x) * sv.x);
  o.y = f2bf(xv.y + (xp.y - xv.y) * sv.y);
  o.z = f2bf(xv.z + (xp.z - xv.z) * sv.z);
  o.w = f2bf(xv.w + (xp.w - xv.w) * sv.w);
  *(ushort4*)(out + e) = o;
}

// ---------------------------------------------------------------- weight cvt-transpose
__global__ __launch_bounds__(256)
void wt_k(const float* __restrict__ W, u16* __restrict__ Wt, int K, int N,
          int Kp) {
  __shared__ u16 tile[32][36];
  const int k0 = blockIdx.x * 32, n0 = blockIdx.y * 32;
  const int tid = threadIdx.x;
  const int r = tid >> 3, c4 = (tid & 7) << 2;
  float4 v = *(const float4*)(W + (size_t)(k0 + r) * N + n0 + c4);
  tile[r][c4 + 0] = f2bf(v.x); tile[r][c4 + 1] = f2bf(v.y);
  tile[r][c4 + 2] = f2bf(v.z); tile[r][c4 + 3] = f2bf(v.w);
  __syncthreads();
  ushort4 o;
  o.x = tile[c4 + 0][r]; o.y = tile[c4 + 1][r];
  o.z = tile[c4 + 2][r]; o.w = tile[c4 + 3][r];
  *(ushort4*)(Wt + (size_t)(n0 + r) * Kp + k0 + c4) = o;
}

// ---------------------------------------------------------------- MFMA GEMM
// C[M,N] = A[M,lda](bf16) * Bt[N,ldb](bf16), fp32 accum. 128x128, BK=64,
// global_load_lds + both-sides XOR swizzle (R13).
enum { EPI_BF = 0, EPI_F32 = 1, EPI_BIAS_SP = 2, EPI_BIAS_SIG = 3,
       EPI_VMIX = 4 };

template<int EPI>
__global__ __launch_bounds__(256)
void mgemm_k(const u16* __restrict__ A, const u16* __restrict__ Bt,
             float* __restrict__ outF, u16* __restrict__ outB,
             int M, int N, int K, int lda, int ldb,
             const float* __restrict__ bias, const u16* __restrict__ p1,
             const float* __restrict__ p2)
{
  __shared__ alignas(16) u16 As[128 * 64];
  __shared__ alignas(16) u16 Bs[128 * 64];
  const int m0 = blockIdx.x * 128;
  const int n0 = blockIdx.y * 128;
  const int tid = threadIdx.x;
  const int lane = tid & 63;
  const int wid = tid >> 6;
  const int wr = wid >> 1, wc = wid & 1;
  f4v acc[4][4];
  #pragma unroll
  for (int i = 0; i < 4; ++i)
    #pragma unroll
    for (int j = 0; j < 4; ++j) acc[i][j] = f4v{0.f, 0.f, 0.f, 0.f};

  const int l15 = lane & 15;
  const int lq = lane >> 4;
  const int nkt = K >> 6;
  for (int kt = 0; kt < nkt; ++kt) {
    const int k0 = kt << 6;
    __syncthreads();
    #pragma unroll
    for (int a = 0; a < 4; ++a) {
      const int blkU = (wid * 4 + a) * 64;
      const int U = blkU + lane;
      const int row = U >> 3;
      const int u = U & 7;
      const int col = ((u ^ (row & 7)) << 3);
      gload16(A  + (size_t)(m0 + row) * lda + k0 + col, &As[blkU * 8]);
      gload16(Bt + (size_t)(n0 + row) * ldb + k0 + col, &Bs[blkU * 8]);
    }
    __syncthreads();
    #pragma unroll
    for (int h = 0; h < 2; ++h) {
      s8v af[4], bfr[4];
      #pragma unroll
      for (int i = 0; i < 4; ++i) {
        const int row = wr * 64 + i * 16 + l15;
        const int u = (h * 4 + lq) ^ (row & 7);
        af[i] = *(const s8v*)&As[row * 64 + u * 8];
      }
      #pragma unroll
      for (int j = 0; j < 4; ++j) {
        const int row = wc * 64 + j * 16 + l15;
        const int u = (h * 4 + lq) ^ (row & 7);
        bfr[j] = *(const s8v*)&Bs[row * 64 + u * 8];
      }
      #pragma unroll
      for (int i = 0; i < 4; ++i)
        #pragma unroll
        for (int j = 0; j < 4; ++j)
          acc[i][j] = __builtin_amdgcn_mfma_f32_16x16x32_bf16(af[i], bfr[j],
                                                              acc[i][j],
                                                              0, 0, 0);
    }
  }
  const int rbase = m0 + wr * 64 + (lq << 2);
  const int cbase = n0 + wc * 64 + l15;
  #pragma unroll
  for (int i = 0; i < 4; ++i) {
    #pragma unroll
    for (int j = 0; j < 4; ++j) {
      f4v c = acc[i][j];
      const int col = cbase + j * 16;
      #pragma unroll
      for (int q = 0; q < 4; ++q) {
        const int row = rbase + i * 16 + q;
        const size_t idx = (size_t)row * N + col;
        const float r = c[q];
        if (EPI == EPI_BF) {
          outB[idx] = f2bf(r);
        } else if (EPI == EPI_F32) {
          outF[idx] = r;
        } else if (EPI == EPI_BIAS_SP) {
          float u = bias[col] + r;
          float z = -u;
          float sp = fmaxf(z, 0.f) + log1pf(expf(-fabsf(z)));
          outB[idx] = f2bf(-sp - 0.5f);
        } else if (EPI == EPI_BIAS_SIG) {
          float u = bias[col] + r;
          outB[idx] = f2bf(1.f / (1.f + expf(-u)));
        } else if (EPI == EPI_VMIX) {
          float u = bias[col] + r;
          float sg = 1.f / (1.f + expf(-u));
          float v = bf2f(p1[idx]);
          float v0v = p2[idx];
          outB[idx] = f2bf(v + (v0v - v) * sg);
        }
      }
    }
  }
}

// ---------------------------------------------------------------- SIMT GEMM (skinny w1 paths)
__global__ __launch_bounds__(256)
void gemm_part_k(const u16* __restrict__ A, const float* __restrict__ W,
                 float* __restrict__ outF, int M, int N, int K, int kchunk,
                 int NP)
{
  __shared__ alignas(16) float As[16][68];
  __shared__ alignas(16) float Bs[16][68];
  const int m0 = blockIdx.x * 64;
  const int n0 = blockIdx.y * 64;
  const int kz = blockIdx.z;
  const int k0base = kz * kchunk;
  const int tid = threadIdx.x;
  const int tx = tid & 15, ty = tid >> 4;
  float acc[4][4] = {{0.f}};
  const int a_m = tid >> 2;
  const int a_k = (tid & 3) << 2;
  const int b_k = tid >> 4;
  const int b_n = (tid & 15) << 2;
  const int niters = kchunk >> 4;
  for (int it = 0; it < niters; ++it) {
    const int k0 = k0base + (it << 4);
    float4 av;
    {
      ushort4 u = *(const ushort4*)(A + (size_t)(m0 + a_m) * K + (k0 + a_k));
      av = make_float4(bf2f(u.x), bf2f(u.y), bf2f(u.z), bf2f(u.w));
    }
    float4 bv;
    {
      int gn = n0 + b_n;
      const float* wp = W + (size_t)(k0 + b_k) * N + gn;
      if (gn + 3 < N) {
        bv = *(const float4*)wp;
      } else {
        bv.x = (gn + 0 < N) ? wp[0] : 0.f;
        bv.y = (gn + 1 < N) ? wp[1] : 0.f;
        bv.z = (gn + 2 < N) ? wp[2] : 0.f;
        bv.w = (gn + 3 < N) ? wp[3] : 0.f;
      }
    }
    __syncthreads();
    As[a_k + 0][a_m] = av.x; As[a_k + 1][a_m] = av.y;
    As[a_k + 2][a_m] = av.z; As[a_k + 3][a_m] = av.w;
    Bs[b_k][b_n + 0] = bv.x; Bs[b_k][b_n + 1] = bv.y;
    Bs[b_k][b_n + 2] = bv.z; Bs[b_k][b_n + 3] = bv.w;
    __syncthreads();
    #pragma unroll
    for (int kk = 0; kk < 16; ++kk) {
      float4 a4 = *(const float4*)&As[kk][ty << 2];
      float4 b4 = *(const float4*)&Bs[kk][tx << 2];
      float ar[4] = {a4.x, a4.y, a4.z, a4.w};
      float br[4] = {b4.x, b4.y, b4.z, b4.w};
      #pragma unroll
      for (int i = 0; i < 4; ++i)
        #pragma unroll
        for (int j = 0; j < 4; ++j)
          acc[i][j] = fmaf(ar[i], br[j], acc[i][j]);
    }
  }
  #pragma unroll
  for (int i = 0; i < 4; ++i) {
    int gm = m0 + (ty << 2) + i;
    #pragma unroll
    for (int j = 0; j < 4; ++j) {
      int gn = n0 + (tx << 2) + j;
      if (gn >= N) continue;
      outF[((size_t)kz * M + gm) * NP + gn] = acc[i][j];
    }
  }
}

// ---------------------------------------------------------------- K-split reduce
__global__ __launch_bounds__(256)
void reduce_k(const float* __restrict__ part, u16* __restrict__ out,
              int M, int D, int NP, int nz, int act, int Dp)
{
  int idx = blockIdx.x * 256 + threadIdx.x;
  if (idx >= M * Dp) return;
  int t = idx / Dp, n = idx - t * Dp;
  float s = 0.f;
  if (n < D) {
    for (int z = 0; z < nz; ++z) s += part[((size_t)z * M + t) * NP + n];
    if (act == 1) s = tanhf(s);
    else if (act == 2) s = 1.f / (1.f + expf(-s));
  }
  out[idx] = f2bf(s);
}

// ---------------------------------------------------------------- fused pair prep
__global__ __launch_bounds__(256)
void prep12_k(const u16* __restrict__ k_in, const u16* __restrict__ a_in,
              const u16* __restrict__ r_in, const u16* __restrict__ w_in,
              const float* __restrict__ kk_s, const float* __restrict__ ka_s,
              u16* __restrict__ ao_out, u16* __restrict__ bo_out,
              u16* __restrict__ k_out, u16* __restrict__ wd_out,
              u16* __restrict__ rw_out, float2* __restrict__ scal,
              float4* __restrict__ scal4)
{
  const int tid = threadIdx.x;
  const int lane = tid & 63;
  const int hpidx = blockIdx.x * 4 + (tid >> 6);  // (b*T/2+tp)*H + h
  const int h = hpidx & (HH - 1);
  const int btp = hpidx >> 5;
  const int tp = btp & (TT / 2 - 1);
  const int b = btp >> 9;                          // TT/2 = 512
  const int c = (h << 6) + lane;
  const size_t be = ((size_t)(b * TT + 2 * tp)) * CC + (h << 6) + lane;
  const size_t bod = be + CC;
  const float ks = kk_s[c], kas = ka_s[c];
  const float k1 = bf2f(k_in[be]),  k2 = bf2f(k_in[bod]);
  const float a1 = bf2f(a_in[be]),  a2 = bf2f(a_in[bod]);
  const float r1 = bf2f(r_in[be]),  r2 = bf2f(r_in[bod]);
  const float wraw1 = bf2f(w_in[be]), wraw2 = bf2f(w_in[bod]);
  float kk1 = k1 * ks, kk2 = k2 * ks;
  float ss1 = kk1 * kk1, ss2 = kk2 * kk2;
  #pragma unroll
  for (int off = 32; off; off >>= 1) {
    ss1 += __shfl_xor(ss1, off, 64);
    ss2 += __shfl_xor(ss2, off, 64);
  }
  const float kkn1 = kk1 / fmaxf(sqrtf(ss1), 1e-12f);
  const float kkn2 = kk2 / fmaxf(sqrtf(ss2), 1e-12f);
  const float kf1 = k1 * (1.f + (a1 - 1.f) * kas);
  const float kf2 = k2 * (1.f + (a2 - 1.f) * kas);
  const float wd1 = expf(-expf(wraw1));
  const float wd2 = expf(-expf(wraw2));
  const float ao1 = -kkn1, ao2 = -kkn2;
  const float bo1 = kkn1 * a1, bo2 = kkn2 * a2;
  const float rw1 = wd1 * r1, rw2 = wd2 * r2;
  float kr1 = kf1 * r1, br1 = bo1 * r1;
  float kr2 = kf2 * r2, br2 = bo2 * r2;
  float cba = bo1 * ao2, ckb = kf1 * ao2;
  float crb = bo1 * rw2, crk = kf1 * rw2;
  #pragma unroll
  for (int off = 32; off; off >>= 1) {
    kr1 += __shfl_xor(kr1, off, 64);  br1 += __shfl_xor(br1, off, 64);
    kr2 += __shfl_xor(kr2, off, 64);  br2 += __shfl_xor(br2, off, 64);
    cba += __shfl_xor(cba, off, 64);  ckb += __shfl_xor(ckb, off, 64);
    crb += __shfl_xor(crb, off, 64);  crk += __shfl_xor(crk, off, 64);
  }
  ao_out[be]  = f2bf(ao1);
  ao_out[bod] = f2bf(wd1 * ao2);
  bo_out[be]  = f2bf(bo1 * wd2);
  bo_out[bod] = f2bf(bo2);
  k_out[be]   = f2bf(kf1);
  k_out[bod]  = f2bf(kf2);
  wd_out[be]  = f2bf(wd1 * wd2);
  wd_out[bod] = f2bf(kf1 * wd2);
  rw_out[be]  = f2bf(rw1);
  rw_out[bod] = f2bf(wd1 * rw2);
  if (lane == 0) {
    const int se = (b * TT + 2 * tp) * HH + h;
    scal[se]      = make_float2(kr1, br1);
    scal[se + HH] = make_float2(kr2, br2);
    scal4[hpidx]  = make_float4(cba, ckb, crb, crk);
  }
}

// ---------------------------------------------------------------- RWKV7 recurrence
// g=16 pair form (R13/R17): one iteration advances TWO timesteps with a
// single 4-level shfl butterfly of 4 interleaved reductions.
__global__ __launch_bounds__(256)
void rec_k(const u16* __restrict__ rw, const u16* __restrict__ wd,
           const u16* __restrict__ kv, const u16* __restrict__ v,
           const u16* __restrict__ ao, const u16* __restrict__ bo,
           const float2* __restrict__ scal, const float4* __restrict__ scal4,
           u16* __restrict__ y)
{
  const int gw = blockIdx.x * 4 + (threadIdx.x >> 6);   // 0..1023
  const int lane = threadIdx.x & 63;
  const int sub = lane & 15;
  const int grp = lane >> 4;
  const int bh = gw >> 4;
  const int rblk = gw & 15;
  const int i = rblk * 4 + grp;
  const int b = bh >> 5, h = bh & (HH - 1);
  const size_t base0 = ((size_t)b * TT) * CC + (h << 6);
  const size_t vecb = base0 + (sub << 2);
  const size_t vb   = base0 + i;
  const int sbase = b * TT * HH + h;
  const int pbase = b * (TT / 2) * HH + h;
  float s0 = 0.f, s1 = 0.f, s2 = 0.f, s3 = 0.f;

  us4 W12, KW1, AO1, WA2, BW1, BO2, RW1, WR2, K2;
  float V1, V2; float2 SE, SO; float4 S4;
#define PLOAD(TP) do {                                                  \
    const size_t be_ = vecb + (size_t)(2 * (TP)) * CC;                  \
    const size_t bo_ = be_ + CC;                                        \
    W12 = *(const us4*)(wd + be_);  KW1 = *(const us4*)(wd + bo_);      \
    AO1 = *(const us4*)(ao + be_);  WA2 = *(const us4*)(ao + bo_);      \
    BW1 = *(const us4*)(bo + be_);  BO2 = *(const us4*)(bo + bo_);      \
    RW1 = *(const us4*)(rw + be_);  WR2 = *(const us4*)(rw + bo_);      \
    K2  = *(const us4*)(kv + bo_);                                      \
    V1 = bf2f(v[vb + (size_t)(2 * (TP)) * CC]);                         \
    V2 = bf2f(v[vb + (size_t)(2 * (TP) + 1) * CC]);                     \
    SE = scal[sbase + (2 * (TP)) * HH];                                 \
    SO = scal[sbase + (2 * (TP) + 1) * HH];                             \
    S4 = scal4[pbase + (TP) * HH];                                      \
  } while (0)

  PLOAD(0);
  for (int tp = 0; tp < TT / 2; ++tp) {
    const float w0 = bf2f(W12[0]), w1 = bf2f(W12[1]),
                w2 = bf2f(W12[2]), w3 = bf2f(W12[3]);
    const float kw0 = bf2f(KW1[0]), kw1_ = bf2f(KW1[1]),
                kw2 = bf2f(KW1[2]), kw3 = bf2f(KW1[3]);
    const float a0 = bf2f(AO1[0]), a1 = bf2f(AO1[1]),
                a2 = bf2f(AO1[2]), a3 = bf2f(AO1[3]);
    const float x0 = bf2f(WA2[0]), x1 = bf2f(WA2[1]),
                x2 = bf2f(WA2[2]), x3 = bf2f(WA2[3]);
    const float bw0 = bf2f(BW1[0]), bw1_ = bf2f(BW1[1]),
                bw2 = bf2f(BW1[2]), bw3 = bf2f(BW1[3]);
    const float b0 = bf2f(BO2[0]), b1 = bf2f(BO2[1]),
                b2 = bf2f(BO2[2]), b3 = bf2f(BO2[3]);
    const float e0 = bf2f(RW1[0]), e1 = bf2f(RW1[1]),
                e2 = bf2f(RW1[2]), e3 = bf2f(RW1[3]);
    const float f0 = bf2f(WR2[0]), f1 = bf2f(WR2[1]),
                f2 = bf2f(WR2[2]), f3 = bf2f(WR2[3]);
    const float k0 = bf2f(K2[0]), k1 = bf2f(K2[1]),
                k2 = bf2f(K2[2]), k3 = bf2f(K2[3]);
    const float v1c = V1, v2c = V2;
    const float kr1 = SE.x, br1 = SE.y, kr2 = SO.x, br2 = SO.y;
    const float cba = S4.x, ckb = S4.y, crb = S4.z, crk = S4.w;
    if (tp + 1 < TT / 2) PLOAD(tp + 1);
    float u1 = fmaf(s3, a3, fmaf(s2, a2, fmaf(s1, a1, s0 * a0)));
    float u2 = fmaf(s3, x3, fmaf(s2, x2, fmaf(s1, x1, s0 * x0)));
    float q1 = fmaf(s3, e3, fmaf(s2, e2, fmaf(s1, e1, s0 * e0)));
    float q2 = fmaf(s3, f3, fmaf(s2, f2, fmaf(s1, f1, s0 * f0)));
    u1 += __shfl_xor(u1, 1, 64);  u2 += __shfl_xor(u2, 1, 64);
    q1 += __shfl_xor(q1, 1, 64);  q2 += __shfl_xor(q2, 1, 64);
    u1 += __shfl_xor(u1, 2, 64);  u2 += __shfl_xor(u2, 2, 64);
    q1 += __shfl_xor(q1, 2, 64);  q2 += __shfl_xor(q2, 2, 64);
    u1 += __shfl_xor(u1, 4, 64);  u2 += __shfl_xor(u2, 4, 64);
    q1 += __shfl_xor(q1, 4, 64);  q2 += __shfl_xor(q2, 4, 64);
    u1 += __shfl_xor(u1, 8, 64);  u2 += __shfl_xor(u2, 8, 64);
    q1 += __shfl_xor(q1, 8, 64);  q2 += __shfl_xor(q2, 8, 64);
    const float sac = fmaf(ckb, v1c, fmaf(cba, u1, u2));
    const float y1 = fmaf(br1, u1, fmaf(kr1, v1c, q1));
    const float y2 = fmaf(br2, sac, fmaf(kr2, v2c,
                       fmaf(crb, u1, fmaf(crk, v1c, q2))));
    s0 = fmaf(v2c, k0, fmaf(v1c, kw0, fmaf(sac, b0, fmaf(u1, bw0, s0 * w0))));
    s1 = fmaf(v2c, k1, fmaf(v1c, kw1_, fmaf(sac, b1, fmaf(u1, bw1_, s1 * w1))));
    s2 = fmaf(v2c, k2, fmaf(v1c, kw2, fmaf(sac, b2, fmaf(u1, bw2, s2 * w2))));
    s3 = fmaf(v2c, k3, fmaf(v1c, kw3, fmaf(sac, b3, fmaf(u1, bw3, s3 * w3))));
    if (sub == 0) {
      y[vb + (size_t)(2 * tp) * CC] = f2bf(y1);
      y[vb + (size_t)(2 * tp + 1) * CC] = f2bf(y2);
    }
  }
#undef PLOAD
}

// ---------------------------------------------------------------- GroupNorm + bonus + gate
__global__ __launch_bounds__(256)
void gn_k(u16* __restrict__ y, const u16* __restrict__ r,
          const u16* __restrict__ k, const u16* __restrict__ v,
          const u16* __restrict__ g, const float* __restrict__ rk_s,
          const float* __restrict__ gn_w, const float* __restrict__ gn_b)
{
  int tid = threadIdx.x, lane = tid & 63, wv = tid >> 6;
  int hidx = blockIdx.x * 4 + wv;
  int h = hidx & (HH - 1);
  int c = (h << 6) + lane;
  size_t base = ((size_t)hidx << 6) + lane;
  float yv = bf2f(y[base]), rv = bf2f(r[base]), kv = bf2f(k[base]);
  float vv = bf2f(v[base]), gv = bf2f(g[base]);
  float bsum = rv * kv * rk_s[c];
  float s1 = yv, s2 = yv * yv;
  for (int off = 32; off; off >>= 1) {
    s1 += __shfl_xor(s1, off, 64);
    s2 += __shfl_xor(s2, off, 64);
    bsum += __shfl_xor(bsum, off, 64);
  }
  float mu = s1 * (1.f / 64.f);
  float var = s2 * (1.f / 64.f) - mu * mu;
  float rstd = rsqrtf(var + 0.00064f);
  float z = (yv - mu) * rstd * gn_w[c] + gn_b[c];
  y[base] = f2bf((z + bsum * vv) * gv);
}

// ---------------------------------------------------------------- helpers
__global__ __launch_bounds__(256)
void copy_v0(const float* __restrict__ v0, float* __restrict__ out) {
  int idx = blockIdx.x * 256 + threadIdx.x;
  ((float4*)out)[idx] = ((const float4*)v0)[idx];
}

__global__ __launch_bounds__(256)
void zero_out(float* __restrict__ out) {
  int idx = blockIdx.x * 256 + threadIdx.x;
  ((float4*)out)[idx] = make_float4(0.f, 0.f, 0.f, 0.f);
}

// ----------------------------------------------------------------
extern "C" void kernel_launch(void* const* d_in, const int* in_sizes, int n_in,
                              void* d_out, int out_size, void* d_ws, size_t ws_size,
                              hipStream_t stream) {
  (void)n_in; (void)out_size;
  const bool dictOrder = (in_sizes[9] == CC);
  int IX[28];
  if (dictOrder) {
    const int m[28] = {0,1,2,3,4,5,6,7, 8,13,14, 9,15,16, 10,17,18, 19,20,
                       11,12,21, 22,23,24,25, 26,27};
    for (int i = 0; i < 28; ++i) IX[i] = m[i];
  } else {
    for (int i = 0; i < 28; ++i) IX[i] = i;
  }
  const float* x     = (const float*)d_in[IX[0]];
  const float* v0    = (const float*)d_in[IX[1]];
  const float* xx_r  = (const float*)d_in[IX[2]];
  const float* xx_w  = (const float*)d_in[IX[3]];
  const float* xx_k  = (const float*)d_in[IX[4]];
  const float* xx_v  = (const float*)d_in[IX[5]];
  const float* xx_a  = (const float*)d_in[IX[6]];
  const float* xx_g  = (const float*)d_in[IX[7]];
  const float* ww_b  = (const float*)d_in[IX[8]];
  const float* ww_w1 = (const float*)d_in[IX[9]];
  const float* ww_w2 = (const float*)d_in[IX[10]];
  const float* aa_b  = (const float*)d_in[IX[11]];
  const float* aa_w1 = (const float*)d_in[IX[12]];
  const float* aa_w2 = (const float*)d_in[IX[13]];
  const float* vv_b  = (const float*)d_in[IX[14]];
  const float* vv_w1 = (const float*)d_in[IX[15]];
  const float* vv_w2 = (const float*)d_in[IX[16]];
  const float* gg_w1 = (const float*)d_in[IX[17]];
  const float* gg_w2 = (const float*)d_in[IX[18]];
  const float* kk_s  = (const float*)d_in[IX[19]];
  const float* ka_s  = (const float*)d_in[IX[20]];
  const float* rk_s  = (const float*)d_in[IX[21]];
  const float* W_r   = (const float*)d_in[IX[22]];
  const float* W_k   = (const float*)d_in[IX[23]];
  const float* W_v   = (const float*)d_in[IX[24]];
  const float* W_o   = (const float*)d_in[IX[25]];
  const float* gn_w  = (const float*)d_in[IX[26]];
  const float* gn_b  = (const float*)d_in[IX[27]];

  const size_t NBTC = (size_t)BT * CC;
  dim3 blk(256);
  const int grid4f = (int)(NBTC / 4 / 256);

  const size_t WS_NEED = 7 * NBTC * sizeof(u16);
  float* outF = (float*)d_out;
  if (ws_size < WS_NEED || d_ws == nullptr) {
    zero_out<<<grid4f, blk, 0, stream>>>(outF);
    copy_v0<<<grid4f, blk, 0, stream>>>(v0, outF + NBTC);
    return;
  }

  // Regions: R0=h1/r  R1=Wt(w2)/kf(kept for gn_k)  R2=v
  // R3=partY/Wt/ao  R4=a/bo/g  R5=w_raw/wd -> partG/Wt(g,o)
  // R6=mix staging/rw.  y (bf16) in d_out v0-slot front half;
  // scal2 + scal4 in its back half.
  u16* W16   = (u16*)d_ws;
  u16* R0 = W16 + 0 * NBTC;
  u16* R1 = W16 + 1 * NBTC;
  u16* R2 = W16 + 2 * NBTC;
  u16* R3 = W16 + 3 * NBTC;
  u16* R4 = W16 + 4 * NBTC;
  u16* R5 = W16 + 5 * NBTC;
  u16* R6 = W16 + 6 * NBTC;
  float* partY = (float*)R3;
  float* partG = (float*)R5;
  u16* ws_y = (u16*)(outF + NBTC);          // bf16 y: front half of v0 slot
  float2* scal = (float2*)(ws_y + NBTC);    // kr/br per (b,t,h)
  float4* scal4 = (float4*)(ws_y + NBTC + (size_t)BT * HH * 4);  // pair scalars

  const int gridMix = (BT * CC / 4) / 256;  // float4 granules (8192)
  dim3 gM(BT / 128, 2048 / 128);            // (32, 16)

  // ---- w path (K=96 padded to 128)
  mix_k<<<gridMix, blk, 0, stream>>>(x, xx_w, R6);
  gemm_part_k<<<dim3(32, 2, 8), blk, 0, stream>>>(R6, ww_w1, partY,
      BT, 96, 2048, 256, 128);
  reduce_k<<<(BT * 128) / 256, blk, 0, stream>>>(partY, R0, BT, 96, 128, 8, 1, 128);
  wt_k<<<dim3(3, 64), blk, 0, stream>>>(ww_w2, R1, 96, 2048, 128);
  mgemm_k<EPI_BIAS_SP><<<gM, blk, 0, stream>>>(R0, R1, nullptr, R5,
      BT, 2048, 128, 128, 128, ww_b, nullptr, nullptr);

  // ---- a path (K=96 padded to 128)
  mix_k<<<gridMix, blk, 0, stream>>>(x, xx_a, R6);
  gemm_part_k<<<dim3(32, 2, 8), blk, 0, stream>>>(R6, aa_w1, partY,
      BT, 96, 2048, 256, 128);
  reduce_k<<<(BT * 128) / 256, blk, 0, stream>>>(partY, R0, BT, 96, 128, 8, 0, 128);
  wt_k<<<dim3(3, 64), blk, 0, stream>>>(aa_w2, R1, 96, 2048, 128);
  mgemm_k<EPI_BIAS_SIG><<<gM, blk, 0, stream>>>(R0, R1, nullptr, R4,
      BT, 2048, 128, 128, 128, aa_b, nullptr, nullptr);

  // ---- v path
  mix_k<<<gridMix, blk, 0, stream>>>(x, xx_v, R6);
  wt_k<<<dim3(64, 64), blk, 0, stream>>>(W_v, R1, 2048, 2048, 2048);
  mgemm_k<EPI_BF><<<gM, blk, 0, stream>>>(R6, R1, nullptr, R2,
      BT, 2048, 2048, 2048, 2048, nullptr, nullptr, nullptr);
  gemm_part_k<<<dim3(32, 1, 8), blk, 0, stream>>>(R6, vv_w1, partY,
      BT, 64, 2048, 256, 64);
  reduce_k<<<(BT * 64) / 256, blk, 0, stream>>>(partY, R0, BT, 64, 64, 8, 0, 64);
  wt_k<<<dim3(2, 64), blk, 0, stream>>>(vv_w2, R1, 64, 2048, 64);
  mgemm_k<EPI_VMIX><<<gM, blk, 0, stream>>>(R0, R1, nullptr, R2,
      BT, 2048, 64, 64, 64, vv_b, R2, v0);

  // ---- k path
  mix_k<<<gridMix, blk, 0, stream>>>(x, xx_k, R6);
  wt_k<<<dim3(64, 64), blk, 0, stream>>>(W_k, R3, 2048, 2048, 2048);
  mgemm_k<EPI_BF><<<gM, blk, 0, stream>>>(R6, R3, nullptr, R1,
      BT, 2048, 2048, 2048, 2048, nullptr, nullptr, nullptr);

  // ---- r path
  mix_k<<<gridMix, blk, 0, stream>>>(x, xx_r, R6);
  wt_k<<<dim3(64, 64), blk, 0, stream>>>(W_r, R3, 2048, 2048, 2048);
  mgemm_k<EPI_BF><<<gM, blk, 0, stream>>>(R6, R3, nullptr, R0,
      BT, 2048, 2048, 2048, 2048, nullptr, nullptr, nullptr);

  // ---- fused prep+pair-compound: k(R1),a(R4),r(R0),w_raw(R5) ->
  //      ao(R3), bo(R4), kf(R1), wd(R5), rw(R6), scal, scal4
  prep12_k<<<(BB * (TT / 2) * HH) / 4, blk, 0, stream>>>(
      R1, R4, R0, R5, kk_s, ka_s, R3, R4, R1, R5, R6, scal, scal4);

  // ---- recurrence (g=16, 2 steps/iter): rw=R6 wd=R5 kv=R1 v=R2 ao=R3 bo=R4
  rec_k<<<256, blk, 0, stream>>>(R6, R5, R1, R2, R3, R4, scal, scal4, ws_y);

  // ---- g path (R5, R3, R4, R6 dead after rec; R1 kf preserved)
  mix_k<<<gridMix, blk, 0, stream>>>(x, xx_g, R6);
  gemm_part_k<<<dim3(32, 4, 2), blk, 0, stream>>>(R6, gg_w1, partG,
      BT, 256, 2048, 1024, 256);
  reduce_k<<<(BT * 256) / 256, blk, 0, stream>>>(partG, R3, BT, 256, 256, 2, 2, 256);
  wt_k<<<dim3(8, 64), blk, 0, stream>>>(gg_w2, R5, 256, 2048, 256);
  mgemm_k<EPI_BF><<<gM, blk, 0, stream>>>(R3, R5, nullptr, R4,
      BT, 2048, 256, 256, 256, nullptr, nullptr, nullptr);

  // ---- groupnorm + bonus + gate (in place on y; k=R1 kf intact)
  gn_k<<<BT * HH / 4, blk, 0, stream>>>(ws_y, R0, R1, R2, R4,
                                        rk_s, gn_w, gn_b);

  // ---- final projection y @ W_o -> fp32 output 0
  wt_k<<<dim3(64, 64), blk, 0, stream>>>(W_o, R5, 2048, 2048, 2048);
  mgemm_k<EPI_F32><<<gM, blk, 0, stream>>>(ws_y, R5, outF, nullptr,
      BT, 2048, 2048, 2048, 2048, nullptr, nullptr, nullptr);

  // ---- v0 passthrough (overwrites y scratch + scal, last)
  copy_v0<<<grid4f, blk, 0, stream>>>(v0, outF + NBTC);
}